// Round 1
// baseline (2631.484 us; speedup 1.0000x reference)
//
#include <hip/hip_runtime.h>
#include <stdint.h>

// ---- problem constants ----
#define B_ 2
#define T_ 2048
#define D_ 512
#define H_ 8
#define HD_ 64
#define V_ 32000
#define L_ 4
#define NL_ 3
#define HID_ 2048
#define NROW 4096          // B*T
#define CCH 64             // chunk timesteps
#define CROWS 128          // rows per chunk (CCH*B)
#define NC 32              // T/CCH
#define EPS_ 1e-5f

typedef __attribute__((ext_vector_type(8))) __bf16 bf16x8;
typedef __attribute__((ext_vector_type(4))) float f32x4;

__device__ __forceinline__ float b2f(unsigned short u) {
  union { uint32_t i; float f; } v; v.i = ((uint32_t)u) << 16; return v.f;
}
__device__ __forceinline__ unsigned short f2b(float f) {
  union { float f; uint32_t i; } v; v.f = f;
  uint32_t u = v.i;
  u += 0x7fffu + ((u >> 16) & 1u);   // RNE
  return (unsigned short)(u >> 16);
}
__device__ __forceinline__ void unpack8(uint4 u, float* dst) {
  dst[0] = b2f((unsigned short)(u.x & 0xffff)); dst[1] = b2f((unsigned short)(u.x >> 16));
  dst[2] = b2f((unsigned short)(u.y & 0xffff)); dst[3] = b2f((unsigned short)(u.y >> 16));
  dst[4] = b2f((unsigned short)(u.z & 0xffff)); dst[5] = b2f((unsigned short)(u.z >> 16));
  dst[6] = b2f((unsigned short)(u.w & 0xffff)); dst[7] = b2f((unsigned short)(u.w >> 16));
}

// ---- weight prep: f32 [R,C] -> bf16 [C,R] (z-batched) ----
__global__ __launch_bounds__(256) void k_transpose_cvt(
    const float* __restrict__ in, unsigned short* __restrict__ out, int R, int C) {
  size_t zoff = (size_t)blockIdx.z * R * C;
  in += zoff; out += zoff;
  __shared__ float tile[32][33];
  int bx = blockIdx.x * 32;   // col base in `in`
  int by = blockIdx.y * 32;   // row base in `in`
  int tx = threadIdx.x & 31;
  int ty = threadIdx.x >> 5;  // 0..7
#pragma unroll
  for (int i = 0; i < 4; i++)
    tile[ty + 8 * i][tx] = in[(size_t)(by + ty + 8 * i) * C + bx + tx];
  __syncthreads();
#pragma unroll
  for (int i = 0; i < 4; i++)
    out[(size_t)(bx + ty + 8 * i) * R + by + tx] = f2b(tile[tx][ty + 8 * i]);
}

// ---- plain f32 -> bf16 convert (emb for head) ----
__global__ __launch_bounds__(256) void k_cvt(const float* __restrict__ in,
                                             unsigned short* __restrict__ out) {
  int base = (blockIdx.x * 256 + threadIdx.x) * 4;
  float4 v = *(const float4*)(in + base);
  unsigned short o[4] = { f2b(v.x), f2b(v.y), f2b(v.z), f2b(v.w) };
  *(uint2*)(out + base) = *(const uint2*)o;
}

// ---- embedding gather + pos ----
__global__ __launch_bounds__(256) void k_embed(
    const float* __restrict__ emb, const float* __restrict__ pos,
    const int* __restrict__ ids, float* __restrict__ x) {
  int i = blockIdx.x * 256 + threadIdx.x;   // float4 groups, NROW*128 total
  int row = i >> 7, cg = i & 127;
  int t = row & (T_ - 1);
  int id = ids[row];
  float4 e = ((const float4*)(emb + (size_t)id * D_))[cg];
  float4 p = ((const float4*)(pos + (size_t)t * D_))[cg];
  float4 r; r.x = e.x + p.x; r.y = e.y + p.y; r.z = e.z + p.z; r.w = e.w + p.w;
  ((float4*)(x + (size_t)row * D_))[cg] = r;
}

// ---- layernorm: f32 row -> bf16 row ----
__global__ __launch_bounds__(128) void k_ln(
    const float* __restrict__ x, const float* __restrict__ g,
    const float* __restrict__ b, unsigned short* __restrict__ out) {
  int row = blockIdx.x;
  int tid = threadIdx.x;              // 128 threads, 4 f32 each
  const float* xr = x + (size_t)row * D_;
  float4 v = ((const float4*)xr)[tid];
  float s = v.x + v.y + v.z + v.w;
#pragma unroll
  for (int o = 32; o >= 1; o >>= 1) s += __shfl_xor(s, o);
  __shared__ float red[2], red2[2];
  int wv = tid >> 6;
  if ((tid & 63) == 0) red[wv] = s;
  __syncthreads();
  float mu = (red[0] + red[1]) * (1.f / D_);
  float dx = v.x - mu, dy = v.y - mu, dz = v.z - mu, dw = v.w - mu;
  float s2 = dx * dx + dy * dy + dz * dz + dw * dw;
#pragma unroll
  for (int o = 32; o >= 1; o >>= 1) s2 += __shfl_xor(s2, o);
  if ((tid & 63) == 0) red2[wv] = s2;
  __syncthreads();
  float var = (red2[0] + red2[1]) * (1.f / D_);
  float rs = rsqrtf(var + EPS_);
  float4 gv = ((const float4*)g)[tid];
  float4 bv = ((const float4*)b)[tid];
  unsigned short o4[4] = { f2b(dx * rs * gv.x + bv.x), f2b(dy * rs * gv.y + bv.y),
                           f2b(dz * rs * gv.z + bv.z), f2b(dw * rs * gv.w + bv.w) };
  *(uint2*)(out + (size_t)row * D_ + tid * 4) = *(const uint2*)o4;
}

// ---- bf16 MFMA GEMM: C[M,N] = A[M,K] @ Bt[N,K]^T, 128x128x64 tiles ----
#define BM 128
#define BN 128
#define BK 64
enum { E_BF16 = 0, E_RES = 1, E_GELU = 2, E_ACC = 3, E_F32 = 4 };

__device__ __forceinline__ void stage_tile(
    const unsigned short* __restrict__ gbase, int ldk, unsigned short* lds,
    int wave, int lane) {
  // 128 rows x 64 cols bf16 (16KB); XOR-swizzle applied on global source side
#pragma unroll
  for (int q = 0; q < 4; q++) {
    int Lb = (q * 4 + wave) << 10;              // wave-uniform LDS byte base
    int L = Lb + lane * 16;                     // this lane's dest byte
    int row = L >> 7;
    int colb = (L & 127) ^ ((row & 7) << 4);    // involutive swizzle
    const unsigned short* gsrc = gbase + (size_t)row * ldk + (colb >> 1);
    __builtin_amdgcn_global_load_lds(
        (const __attribute__((address_space(1))) uint32_t*)gsrc,
        (__attribute__((address_space(3))) uint32_t*)(lds + (Lb >> 1)),
        16, 0, 0);
  }
}

template <int EPI>
__global__ __launch_bounds__(256) void k_gemm(
    const unsigned short* __restrict__ A,   // [M,K] bf16
    const unsigned short* __restrict__ Bt,  // [N,K] bf16 (+ z*sB)
    const float* __restrict__ bias,         // per-col bias, or resid [M,N]
    void* __restrict__ Out,
    int K, int N, long sB, long sOut, int sBias) {
  int z = blockIdx.z;
  Bt += (size_t)z * sB;
  bias += (size_t)z * sBias;
  int lane = threadIdx.x & 63, wave = threadIdx.x >> 6;
  int wm = wave >> 1, wn = wave & 1;

  __shared__ __align__(16) unsigned short As[2][BM * BK];
  __shared__ __align__(16) unsigned short Bs[2][BN * BK];

  const unsigned short* Ab = A + (size_t)blockIdx.y * BM * K;
  const unsigned short* Bb = Bt + (size_t)blockIdx.x * BN * K;

  f32x4 acc[4][4] = {};
  int nk = K / BK;
  stage_tile(Ab, K, As[0], wave, lane);
  stage_tile(Bb, K, Bs[0], wave, lane);
  __syncthreads();

  for (int kt = 0; kt < nk; kt++) {
    int cur = kt & 1;
    if (kt + 1 < nk) {
      stage_tile(Ab + (size_t)(kt + 1) * BK, K, As[cur ^ 1], wave, lane);
      stage_tile(Bb + (size_t)(kt + 1) * BK, K, Bs[cur ^ 1], wave, lane);
    }
    const char* Ac = (const char*)As[cur];
    const char* Bc = (const char*)Bs[cur];
#pragma unroll
    for (int kk = 0; kk < 2; kk++) {
      bf16x8 af[4], bfr[4];
#pragma unroll
      for (int mt = 0; mt < 4; mt++) {
        int row = wm * 64 + mt * 16 + (lane & 15);
        int off = ((row << 7) | (kk * 64 + ((lane >> 4) << 4))) ^ ((row & 7) << 4);
        af[mt] = *(const bf16x8*)(Ac + off);
      }
#pragma unroll
      for (int nt = 0; nt < 4; nt++) {
        int row = wn * 64 + nt * 16 + (lane & 15);
        int off = ((row << 7) | (kk * 64 + ((lane >> 4) << 4))) ^ ((row & 7) << 4);
        bfr[nt] = *(const bf16x8*)(Bc + off);
      }
#pragma unroll
      for (int mt = 0; mt < 4; mt++)
#pragma unroll
        for (int nt = 0; nt < 4; nt++)
          acc[mt][nt] = __builtin_amdgcn_mfma_f32_16x16x32_bf16(
              af[mt], bfr[nt], acc[mt][nt], 0, 0, 0);
    }
    __syncthreads();
  }

  int gm = blockIdx.y * BM + wm * 64;
  int gn = blockIdx.x * BN + wn * 64;
#pragma unroll
  for (int mt = 0; mt < 4; mt++) {
#pragma unroll
    for (int nt = 0; nt < 4; nt++) {
      int m0 = gm + mt * 16 + ((lane >> 4) << 2);
      int n = gn + nt * 16 + (lane & 15);
#pragma unroll
      for (int j = 0; j < 4; j++) {
        float v = acc[mt][nt][j];
        size_t idx = (size_t)(m0 + j) * N + n;
        if constexpr (EPI == E_BF16) {
          ((unsigned short*)Out)[(size_t)z * sOut + idx] = f2b(v);
        } else if constexpr (EPI == E_RES) {
          ((float*)Out)[idx] = bias[idx] + v;
        } else if constexpr (EPI == E_GELU) {
          v += bias[n];
          float u2 = 1.5957691216057308f * (v + 0.044715f * v * v * v);
          float sg = 1.f / (1.f + __expf(-u2));       // 0.5*(1+tanh(u)) = sigmoid(2u)
          ((unsigned short*)Out)[(size_t)z * sOut + idx] = f2b(v * sg);
        } else if constexpr (EPI == E_ACC) {
          ((float*)Out)[idx] += v + bias[n];
        } else {
          ((float*)Out)[idx] = v;
        }
      }
    }
  }
}

// ---- attention phase A: per-chunk G[c,h,d,k] = 0.5 * sum_{rows} v_d * k_k ----
__global__ __launch_bounds__(256) void k_attnA(
    const unsigned short* __restrict__ kbuf, const unsigned short* __restrict__ vbuf,
    float* __restrict__ G) {
  int c = blockIdx.x, h = blockIdx.y;
  __shared__ __align__(16) float Ks[CROWS][HD_];
  __shared__ __align__(16) float Vs[CROWS][HD_];
  int tid = threadIdx.x;
#pragma unroll
  for (int it = 0; it < 4; it++) {
    int gi = it * 256 + tid;                 // 1024 groups of 8 bf16
    int r = gi >> 3, c8 = gi & 7;
    int bb = r & 1, tt = c * CCH + (r >> 1);
    size_t goff = ((size_t)bb * T_ + tt) * D_ + h * HD_ + c8 * 8;
    uint4 kv = *(const uint4*)(kbuf + goff);
    uint4 vv = *(const uint4*)(vbuf + goff);
    unpack8(kv, &Ks[r][c8 * 8]);
    unpack8(vv, &Vs[r][c8 * 8]);
  }
  __syncthreads();
  int d = tid & 63, kb = (tid >> 6) * 16;    // kb wave-uniform -> broadcast reads
  float acc[16] = {};
  for (int r = 0; r < CROWS; r++) {
    float vd = Vs[r][d];
#pragma unroll
    for (int j = 0; j < 16; j++) acc[j] += vd * Ks[r][kb + j];
  }
  float* Gp = G + (((size_t)c * H_ + h) * HD_ + d) * HD_ + kb;
#pragma unroll
  for (int j = 0; j < 16; j++) Gp[j] = 0.5f * acc[j];
}

// ---- attention phase B: exclusive prefix over chunks ----
__global__ __launch_bounds__(256) void k_attnB(const float* __restrict__ G,
                                               float* __restrict__ Mem) {
  int h = blockIdx.x, tid = threadIdx.x;     // each thread: 16 of 4096 entries
  float4 m[4] = {};
  for (int c = 0; c < NC; c++) {
    size_t off = ((size_t)c * H_ + h) * (HD_ * HD_) + (size_t)tid * 16;
    float4* Mp = (float4*)(Mem + off);
    const float4* Gp = (const float4*)(G + off);
#pragma unroll
    for (int j = 0; j < 4; j++) Mp[j] = m[j];
#pragma unroll
    for (int j = 0; j < 4; j++) {
      float4 gv = Gp[j];
      m[j].x += gv.x; m[j].y += gv.y; m[j].z += gv.z; m[j].w += gv.w;
    }
  }
}

// ---- attention phase C: y = q @ Mem^T + causal(QK^T)@V * 0.5 ----
__global__ __launch_bounds__(128) void k_attnC(
    const unsigned short* __restrict__ qbuf, const unsigned short* __restrict__ kbuf,
    const unsigned short* __restrict__ vbuf, const float* __restrict__ Mem,
    unsigned short* __restrict__ ybuf) {
  int c = blockIdx.x, h = blockIdx.y;
  __shared__ __align__(16) float Ks[CROWS][HD_ + 4];
  __shared__ __align__(16) float Vs[CROWS][HD_ + 4];
  __shared__ __align__(16) float Ms[HD_ * HD_];
  int tid = threadIdx.x;                     // 128 threads: one per row
#pragma unroll
  for (int it = 0; it < 8; it++) {
    int gi = it * 128 + tid;
    int r = gi >> 3, c8 = gi & 7;
    int bb = r & 1, tt = c * CCH + (r >> 1);
    size_t goff = ((size_t)bb * T_ + tt) * D_ + h * HD_ + c8 * 8;
    uint4 kv = *(const uint4*)(kbuf + goff);
    uint4 vv = *(const uint4*)(vbuf + goff);
    unpack8(kv, &Ks[r][c8 * 8]);
    unpack8(vv, &Vs[r][c8 * 8]);
  }
  {
    const float4* Mp = (const float4*)(Mem + ((size_t)c * H_ + h) * (HD_ * HD_));
    float4* Msp = (float4*)Ms;
#pragma unroll
    for (int i = 0; i < 8; i++) Msp[i * 128 + tid] = Mp[i * 128 + tid];
  }
  __syncthreads();

  int r = tid, bb = r & 1, tl = r >> 1;
  const unsigned short* qp = qbuf + ((size_t)bb * T_ + c * CCH + tl) * D_ + h * HD_;
  float q[HD_];
#pragma unroll
  for (int i = 0; i < 8; i++) unpack8(*(const uint4*)(qp + i * 8), &q[i * 8]);

  float y[HD_];
#pragma unroll
  for (int d = 0; d < HD_; d++) {            // y = Ms @ q  (broadcast LDS reads)
    float s = 0.f;
    const float4* Mr = (const float4*)(Ms + d * HD_);
#pragma unroll
    for (int k4 = 0; k4 < 16; k4++) {
      float4 mv = Mr[k4];
      s += mv.x * q[k4 * 4] + mv.y * q[k4 * 4 + 1] + mv.z * q[k4 * 4 + 2] + mv.w * q[k4 * 4 + 3];
    }
    y[d] = s;
  }

  int smax = ((tid >> 6) + 1) * 64;          // wave0: 64 keys, wave1: 128 keys
  for (int s = 0; s < smax; s++) {
    const float4* Kr = (const float4*)(&Ks[s][0]);
    float sc = 0.f;
#pragma unroll
    for (int k4 = 0; k4 < 16; k4++) {
      float4 kv = Kr[k4];
      sc += kv.x * q[k4 * 4] + kv.y * q[k4 * 4 + 1] + kv.z * q[k4 * 4 + 2] + kv.w * q[k4 * 4 + 3];
    }
    sc *= 0.5f;
    if ((s >> 1) <= tl) {
      const float4* Vr = (const float4*)(&Vs[s][0]);
#pragma unroll
      for (int d4 = 0; d4 < 16; d4++) {
        float4 vv = Vr[d4];
        y[d4 * 4]     += sc * vv.x;
        y[d4 * 4 + 1] += sc * vv.y;
        y[d4 * 4 + 2] += sc * vv.z;
        y[d4 * 4 + 3] += sc * vv.w;
      }
    }
  }
  unsigned short* yp = ybuf + ((size_t)bb * T_ + c * CCH + tl) * D_ + h * HD_;
#pragma unroll
  for (int i = 0; i < 32; i++) {
    uint32_t pk = (uint32_t)f2b(y[2 * i]) | ((uint32_t)f2b(y[2 * i + 1]) << 16);
    ((uint32_t*)yp)[i] = pk;
  }
}

// ---- x += cmsacc / 3 ----
__global__ __launch_bounds__(256) void k_combine(float* __restrict__ x,
                                                 const float* __restrict__ a) {
  int i = blockIdx.x * 256 + threadIdx.x;
  float4 xv = ((float4*)x)[i];
  float4 av = ((const float4*)a)[i];
  const float k = 1.f / 3.f;
  xv.x += av.x * k; xv.y += av.y * k; xv.z += av.z * k; xv.w += av.w * k;
  ((float4*)x)[i] = xv;
}

extern "C" void kernel_launch(void* const* d_in, const int* in_sizes, int n_in,
                              void* d_out, int out_size, void* d_ws, size_t ws_size,
                              hipStream_t stream) {
  (void)in_sizes; (void)n_in; (void)out_size; (void)ws_size;
  const float* emb  = (const float*)d_in[0];
  const float* pos  = (const float*)d_in[1];
  const float* ln1g = (const float*)d_in[2];
  const float* ln1b = (const float*)d_in[3];
  const float* Wq   = (const float*)d_in[4];
  const float* Wk   = (const float*)d_in[5];
  const float* Wv   = (const float*)d_in[6];
  const float* Wo   = (const float*)d_in[7];
  const float* ln2g = (const float*)d_in[8];
  const float* ln2b = (const float*)d_in[9];
  const float* W1   = (const float*)d_in[10];
  const float* b1   = (const float*)d_in[11];
  const float* W2   = (const float*)d_in[12];
  const float* b2   = (const float*)d_in[13];
  const float* lnfg = (const float*)d_in[14];
  const float* lnfb = (const float*)d_in[15];
  const int*   ids  = (const int*)d_in[16];

  char* w = (char*)d_ws;
  size_t off = 0;
  auto alloc = [&](size_t bytes) -> void* {
    void* p = w + off; off += (bytes + 255) & ~(size_t)255; return p;
  };
  const size_t DD = (size_t)D_ * D_;
  unsigned short* WqkvT = (unsigned short*)alloc(3ull * L_ * DD * 2);
  unsigned short* WoT   = (unsigned short*)alloc((size_t)L_ * DD * 2);
  unsigned short* W1T   = (unsigned short*)alloc((size_t)L_ * NL_ * D_ * HID_ * 2);
  unsigned short* W2T   = (unsigned short*)alloc((size_t)L_ * NL_ * D_ * HID_ * 2);
  unsigned short* embB  = (unsigned short*)alloc((size_t)V_ * D_ * 2);
  float* x              = (float*)alloc((size_t)NROW * D_ * 4);
  unsigned short* h     = (unsigned short*)alloc((size_t)NROW * D_ * 2);
  unsigned short* qkv   = (unsigned short*)alloc(3ull * NROW * D_ * 2);
  unsigned short* ybuf  = (unsigned short*)alloc((size_t)NROW * D_ * 2);
  unsigned short* hmid  = (unsigned short*)alloc((size_t)NROW * HID_ * 2);
  float* cmsacc         = (float*)alloc((size_t)NROW * D_ * 4);
  float* G              = (float*)alloc((size_t)NC * H_ * HD_ * HD_ * 4);
  float* Mem            = (float*)alloc((size_t)NC * H_ * HD_ * HD_ * 4);
  // total ~155 MB of ws

  dim3 blk(256);
  // weight prep (every call; deterministic)
  k_transpose_cvt<<<dim3(16, 16, L_), blk, 0, stream>>>(Wq, WqkvT + 0 * L_ * DD, D_, D_);
  k_transpose_cvt<<<dim3(16, 16, L_), blk, 0, stream>>>(Wk, WqkvT + 1 * L_ * DD, D_, D_);
  k_transpose_cvt<<<dim3(16, 16, L_), blk, 0, stream>>>(Wv, WqkvT + 2 * L_ * DD, D_, D_);
  k_transpose_cvt<<<dim3(16, 16, L_), blk, 0, stream>>>(Wo, WoT, D_, D_);
  k_transpose_cvt<<<dim3(HID_ / 32, D_ / 32, L_ * NL_), blk, 0, stream>>>(W1, W1T, D_, HID_);
  k_transpose_cvt<<<dim3(D_ / 32, HID_ / 32, L_ * NL_), blk, 0, stream>>>(W2, W2T, HID_, D_);
  k_cvt<<<dim3(V_ * D_ / 1024), blk, 0, stream>>>(emb, embB);

  k_embed<<<dim3(NROW * D_ / 4 / 256), blk, 0, stream>>>(emb, pos, ids, x);

  unsigned short* qb = qkv;
  unsigned short* kb = qkv + (size_t)NROW * D_;
  unsigned short* vb = qkv + 2ull * NROW * D_;

  for (int l = 0; l < L_; l++) {
    k_ln<<<dim3(NROW), dim3(128), 0, stream>>>(x, ln1g + l * D_, ln1b + l * D_, h);
    k_gemm<E_BF16><<<dim3(D_ / BN, NROW / BM, 3), blk, 0, stream>>>(
        h, WqkvT + l * DD, x, qkv, D_, D_, (long)(L_ * DD), (long)((size_t)NROW * D_), 0);
    k_attnA<<<dim3(NC, H_), blk, 0, stream>>>(kb, vb, G);
    k_attnB<<<dim3(H_), blk, 0, stream>>>(G, Mem);
    k_attnC<<<dim3(NC, H_), dim3(128), 0, stream>>>(qb, kb, vb, Mem, ybuf);
    k_gemm<E_RES><<<dim3(D_ / BN, NROW / BM, 1), blk, 0, stream>>>(
        ybuf, WoT + l * DD, x, x, D_, D_, 0, 0, 0);
    k_ln<<<dim3(NROW), dim3(128), 0, stream>>>(x, ln2g + l * D_, ln2b + l * D_, h);
    hipMemsetAsync(cmsacc, 0, (size_t)NROW * D_ * 4, stream);
    for (int n = 0; n < NL_; n++) {
      size_t wo = (size_t)l * NL_ + n;
      k_gemm<E_GELU><<<dim3(HID_ / BN, NROW / BM, 1), blk, 0, stream>>>(
          h, W1T + wo * D_ * HID_, b1 + wo * HID_, hmid, D_, HID_, 0, 0, 0);
      k_gemm<E_ACC><<<dim3(D_ / BN, NROW / BM, 1), blk, 0, stream>>>(
          hmid, W2T + wo * D_ * HID_, b2 + wo * D_, cmsacc, HID_, D_, 0, 0, 0);
    }
    k_combine<<<dim3(NROW * D_ / 4 / 256), blk, 0, stream>>>(x, cmsacc);
  }
  k_ln<<<dim3(NROW), dim3(128), 0, stream>>>(x, lnfg, lnfb, h);
  k_gemm<E_F32><<<dim3(V_ / BN, NROW / BM, 1), blk, 0, stream>>>(
      h, embB, (const float*)x, d_out, D_, V_, 0, 0, 0);
}

// Round 2
// 2492.746 us; speedup vs baseline: 1.0557x; 1.0557x over previous
//
#include <hip/hip_runtime.h>
#include <stdint.h>

// ---- problem constants ----
#define B_ 2
#define T_ 2048
#define D_ 512
#define H_ 8
#define HD_ 64
#define V_ 32000
#define L_ 4
#define NL_ 3
#define HID_ 2048
#define NROW 4096          // B*T
#define CCH 64             // chunk timesteps
#define CROWS 128          // rows per chunk (CCH*B)
#define NC 32              // T/CCH
#define EPS_ 1e-5f

typedef __attribute__((ext_vector_type(8))) __bf16 bf16x8;
typedef __attribute__((ext_vector_type(4))) float f32x4;

__device__ __forceinline__ float b2f(unsigned short u) {
  union { uint32_t i; float f; } v; v.i = ((uint32_t)u) << 16; return v.f;
}
__device__ __forceinline__ unsigned short f2b(float f) {
  union { float f; uint32_t i; } v; v.f = f;
  uint32_t u = v.i;
  u += 0x7fffu + ((u >> 16) & 1u);   // RNE
  return (unsigned short)(u >> 16);
}
__device__ __forceinline__ void unpack8(uint4 u, float* dst) {
  dst[0] = b2f((unsigned short)(u.x & 0xffff)); dst[1] = b2f((unsigned short)(u.x >> 16));
  dst[2] = b2f((unsigned short)(u.y & 0xffff)); dst[3] = b2f((unsigned short)(u.y >> 16));
  dst[4] = b2f((unsigned short)(u.z & 0xffff)); dst[5] = b2f((unsigned short)(u.z >> 16));
  dst[6] = b2f((unsigned short)(u.w & 0xffff)); dst[7] = b2f((unsigned short)(u.w >> 16));
}

// ---- weight prep: f32 [R,C] -> bf16 [C,R] (z-batched) ----
__global__ __launch_bounds__(256) void k_transpose_cvt(
    const float* __restrict__ in, unsigned short* __restrict__ out, int R, int C) {
  size_t zoff = (size_t)blockIdx.z * R * C;
  in += zoff; out += zoff;
  __shared__ float tile[32][33];
  int bx = blockIdx.x * 32;   // col base in `in`
  int by = blockIdx.y * 32;   // row base in `in`
  int tx = threadIdx.x & 31;
  int ty = threadIdx.x >> 5;  // 0..7
#pragma unroll
  for (int i = 0; i < 4; i++)
    tile[ty + 8 * i][tx] = in[(size_t)(by + ty + 8 * i) * C + bx + tx];
  __syncthreads();
#pragma unroll
  for (int i = 0; i < 4; i++)
    out[(size_t)(bx + ty + 8 * i) * R + by + tx] = f2b(tile[tx][ty + 8 * i]);
}

// ---- W2 prep: in[z=(l,n)][HID][D] -> out[l][d][n*HID+k] bf16 (K-concat layout) ----
__global__ __launch_bounds__(256) void k_transpose_w2(
    const float* __restrict__ in, unsigned short* __restrict__ out) {
  int z = blockIdx.z;                 // l*NL + n
  int l = z / NL_, n = z - l * NL_;
  in += (size_t)z * HID_ * D_;
  __shared__ float tile[32][33];
  int bx = blockIdx.x * 32;   // d base
  int by = blockIdx.y * 32;   // k base
  int tx = threadIdx.x & 31;
  int ty = threadIdx.x >> 5;
#pragma unroll
  for (int i = 0; i < 4; i++)
    tile[ty + 8 * i][tx] = in[(size_t)(by + ty + 8 * i) * D_ + bx + tx];
  __syncthreads();
#pragma unroll
  for (int i = 0; i < 4; i++)
    out[((size_t)l * D_ + bx + ty + 8 * i) * (NL_ * HID_) + n * HID_ + by + tx] =
        f2b(tile[tx][ty + 8 * i]);
}

// ---- plain f32 -> bf16 convert (emb for head) ----
__global__ __launch_bounds__(256) void k_cvt(const float* __restrict__ in,
                                             unsigned short* __restrict__ out) {
  int base = (blockIdx.x * 256 + threadIdx.x) * 4;
  float4 v = *(const float4*)(in + base);
  unsigned short o[4] = { f2b(v.x), f2b(v.y), f2b(v.z), f2b(v.w) };
  *(uint2*)(out + base) = *(const uint2*)o;
}

// ---- bsum[l][d] = sum_n b2[l][n][d] ----
__global__ __launch_bounds__(512) void k_bsum(const float* __restrict__ b2,
                                              float* __restrict__ bsum) {
  int l = blockIdx.x, d = threadIdx.x;
  float s = 0.f;
#pragma unroll
  for (int n = 0; n < NL_; n++) s += b2[((size_t)l * NL_ + n) * D_ + d];
  bsum[(size_t)l * D_ + d] = s;
}

// ---- embedding gather + pos ----
__global__ __launch_bounds__(256) void k_embed(
    const float* __restrict__ emb, const float* __restrict__ pos,
    const int* __restrict__ ids, float* __restrict__ x) {
  int i = blockIdx.x * 256 + threadIdx.x;   // float4 groups, NROW*128 total
  int row = i >> 7, cg = i & 127;
  int t = row & (T_ - 1);
  int id = ids[row];
  float4 e = ((const float4*)(emb + (size_t)id * D_))[cg];
  float4 p = ((const float4*)(pos + (size_t)t * D_))[cg];
  float4 r; r.x = e.x + p.x; r.y = e.y + p.y; r.z = e.z + p.z; r.w = e.w + p.w;
  ((float4*)(x + (size_t)row * D_))[cg] = r;
}

// ---- layernorm: f32 row -> bf16 row ----
__global__ __launch_bounds__(128) void k_ln(
    const float* __restrict__ x, const float* __restrict__ g,
    const float* __restrict__ b, unsigned short* __restrict__ out) {
  int row = blockIdx.x;
  int tid = threadIdx.x;              // 128 threads, 4 f32 each
  const float* xr = x + (size_t)row * D_;
  float4 v = ((const float4*)xr)[tid];
  float s = v.x + v.y + v.z + v.w;
#pragma unroll
  for (int o = 32; o >= 1; o >>= 1) s += __shfl_xor(s, o);
  __shared__ float red[2], red2[2];
  int wv = tid >> 6;
  if ((tid & 63) == 0) red[wv] = s;
  __syncthreads();
  float mu = (red[0] + red[1]) * (1.f / D_);
  float dx = v.x - mu, dy = v.y - mu, dz = v.z - mu, dw = v.w - mu;
  float s2 = dx * dx + dy * dy + dz * dz + dw * dw;
#pragma unroll
  for (int o = 32; o >= 1; o >>= 1) s2 += __shfl_xor(s2, o);
  if ((tid & 63) == 0) red2[wv] = s2;
  __syncthreads();
  float var = (red2[0] + red2[1]) * (1.f / D_);
  float rs = rsqrtf(var + EPS_);
  float4 gv = ((const float4*)g)[tid];
  float4 bv = ((const float4*)b)[tid];
  unsigned short o4[4] = { f2b(dx * rs * gv.x + bv.x), f2b(dy * rs * gv.y + bv.y),
                           f2b(dz * rs * gv.z + bv.z), f2b(dw * rs * gv.w + bv.w) };
  *(uint2*)(out + (size_t)row * D_ + tid * 4) = *(const uint2*)o4;
}

// ---- bf16 MFMA GEMM: C[M,N] = A[M,K] @ Bt[N,K]^T, 128x128x64 tiles ----
// Single-buffered (32KB LDS -> ~4 blocks/CU; m132 lesson: 64KB dbuf -> 2/CU regression)
#define BM 128
#define BN 128
#define BK 64
enum { E_BF16 = 0, E_RES = 1, E_GELU = 2, E_CMS = 3, E_F32 = 4 };

__device__ __forceinline__ void stage_tile(
    const unsigned short* __restrict__ gbase, int ldk, unsigned short* lds,
    int wave, int lane) {
  // 128 rows x 64 cols bf16 (16KB); XOR-swizzle applied on global source side
#pragma unroll
  for (int q = 0; q < 4; q++) {
    int Lb = (q * 4 + wave) << 10;              // wave-uniform LDS byte base
    int L = Lb + lane * 16;                     // this lane's dest byte
    int row = L >> 7;
    int colb = (L & 127) ^ ((row & 7) << 4);    // involutive swizzle
    const unsigned short* gsrc = gbase + (size_t)row * ldk + (colb >> 1);
    __builtin_amdgcn_global_load_lds(
        (const __attribute__((address_space(1))) uint32_t*)gsrc,
        (__attribute__((address_space(3))) uint32_t*)(lds + (Lb >> 1)),
        16, 0, 0);
  }
}

template <int EPI>
__global__ __launch_bounds__(256, 4) void k_gemm(
    const unsigned short* __restrict__ A,   // [M,K] bf16
    const unsigned short* __restrict__ Bt,  // [N,K] bf16 (+ z*sB)
    const float* __restrict__ bias,         // per-col bias, or resid [M,N]
    void* __restrict__ Out,
    int K, int N, int ldOut, long sB, long sOut, int sBias) {
  int z = blockIdx.z;
  Bt += (size_t)z * sB;
  bias += (size_t)z * sBias;
  int lane = threadIdx.x & 63, wave = threadIdx.x >> 6;
  int wm = wave >> 1, wn = wave & 1;

  int bx = blockIdx.x, by = blockIdx.y;
  if constexpr (EPI == E_F32) {
    // supertile remap for L2/L3 reuse of the 32MB embB panel (25 x-tiles/group)
    int lin = blockIdx.y * gridDim.x + blockIdx.x;
    int seg = lin / (25 * 32), rem = lin % (25 * 32);
    bx = seg * 25 + rem % 25;  by = rem / 25;
  }

  __shared__ __align__(16) unsigned short As[BM * BK];
  __shared__ __align__(16) unsigned short Bs[BN * BK];

  const unsigned short* Ab = A + (size_t)by * BM * K;
  const unsigned short* Bb = Bt + (size_t)bx * BN * K;

  f32x4 acc[4][4] = {};
  int nk = K / BK;

  for (int kt = 0; kt < nk; kt++) {
    stage_tile(Ab + (size_t)kt * BK, K, As, wave, lane);
    stage_tile(Bb + (size_t)kt * BK, K, Bs, wave, lane);
    __syncthreads();                 // compiler drains vmcnt here -> tiles visible
    const char* Ac = (const char*)As;
    const char* Bc = (const char*)Bs;
#pragma unroll
    for (int kk = 0; kk < 2; kk++) {
      bf16x8 af[4], bfr[4];
#pragma unroll
      for (int mt = 0; mt < 4; mt++) {
        int row = wm * 64 + mt * 16 + (lane & 15);
        int off = ((row << 7) | (kk * 64 + ((lane >> 4) << 4))) ^ ((row & 7) << 4);
        af[mt] = *(const bf16x8*)(Ac + off);
      }
#pragma unroll
      for (int nt = 0; nt < 4; nt++) {
        int row = wn * 64 + nt * 16 + (lane & 15);
        int off = ((row << 7) | (kk * 64 + ((lane >> 4) << 4))) ^ ((row & 7) << 4);
        bfr[nt] = *(const bf16x8*)(Bc + off);
      }
#pragma unroll
      for (int mt = 0; mt < 4; mt++)
#pragma unroll
        for (int nt = 0; nt < 4; nt++)
          acc[mt][nt] = __builtin_amdgcn_mfma_f32_16x16x32_bf16(
              af[mt], bfr[nt], acc[mt][nt], 0, 0, 0);
    }
    __syncthreads();                 // protect LDS before next stage overwrites
  }

  int gm = by * BM + wm * 64;
  int gn = bx * BN + wn * 64;

  if constexpr (EPI == E_F32) {
    // coalesced f32 store: per-wave LDS transpose, 16 rows per pass
    float* Ls = (float*)(wave < 2 ? (void*)As : (void*)Bs) + (wave & 1) * 2048;
#pragma unroll
    for (int mt = 0; mt < 4; mt++) {
#pragma unroll
      for (int nt = 0; nt < 4; nt++)
#pragma unroll
        for (int j = 0; j < 4; j++)
          Ls[(((lane >> 4) << 2) + j) * 68 + nt * 16 + (lane & 15)] = acc[mt][nt][j];
      __syncthreads();               // same-wave LDS order is safe; barrier for rigor
#pragma unroll
      for (int ri = 0; ri < 4; ri++) {
        int rr = ri * 4 + (lane >> 4);
        int cb = (lane & 15) * 4;
        float4 v = *(const float4*)&Ls[rr * 68 + cb];
        *(float4*)&((float*)Out)[(size_t)(gm + mt * 16 + rr) * N + gn + cb] = v;
      }
    }
  } else {
#pragma unroll
    for (int mt = 0; mt < 4; mt++) {
#pragma unroll
      for (int nt = 0; nt < 4; nt++) {
        int m0 = gm + mt * 16 + ((lane >> 4) << 2);
        int n = gn + nt * 16 + (lane & 15);
#pragma unroll
        for (int j = 0; j < 4; j++) {
          float v = acc[mt][nt][j];
          size_t idx = (size_t)z * sOut + (size_t)(m0 + j) * ldOut + n;
          if constexpr (EPI == E_BF16) {
            ((unsigned short*)Out)[idx] = f2b(v);
          } else if constexpr (EPI == E_RES) {
            ((float*)Out)[idx] = bias[idx] + v;
          } else if constexpr (EPI == E_GELU) {
            v += bias[n];
            float u2 = 1.5957691216057308f * (v + 0.044715f * v * v * v);
            float sg = 1.f / (1.f + __expf(-u2));     // tanh-approx GELU
            ((unsigned short*)Out)[idx] = f2b(v * sg);
          } else {  // E_CMS: x += (acc + bsum)/3
            ((float*)Out)[idx] += (v + bias[n]) * (1.f / 3.f);
          }
        }
      }
    }
  }
}

// ---- attention phase A: per-chunk G[c,h,d,k] = 0.5 * sum_{rows} v_d * k_k ----
__global__ __launch_bounds__(256) void k_attnA(
    const unsigned short* __restrict__ kbuf, const unsigned short* __restrict__ vbuf,
    float* __restrict__ G) {
  int c = blockIdx.x, h = blockIdx.y;
  __shared__ __align__(16) float Ks[CROWS][HD_];
  __shared__ __align__(16) float Vs[CROWS][HD_];
  int tid = threadIdx.x;
#pragma unroll
  for (int it = 0; it < 4; it++) {
    int gi = it * 256 + tid;                 // 1024 groups of 8 bf16
    int r = gi >> 3, c8 = gi & 7;
    int bb = r & 1, tt = c * CCH + (r >> 1);
    size_t goff = ((size_t)bb * T_ + tt) * D_ + h * HD_ + c8 * 8;
    uint4 kv = *(const uint4*)(kbuf + goff);
    uint4 vv = *(const uint4*)(vbuf + goff);
    unpack8(kv, &Ks[r][c8 * 8]);
    unpack8(vv, &Vs[r][c8 * 8]);
  }
  __syncthreads();
  int d = tid & 63, kb = (tid >> 6) * 16;    // kb wave-uniform -> broadcast reads
  float acc[16] = {};
  for (int r = 0; r < CROWS; r++) {
    float vd = Vs[r][d];
#pragma unroll
    for (int j = 0; j < 16; j++) acc[j] += vd * Ks[r][kb + j];
  }
  float* Gp = G + (((size_t)c * H_ + h) * HD_ + d) * HD_ + kb;
#pragma unroll
  for (int j = 0; j < 16; j++) Gp[j] = 0.5f * acc[j];
}

// ---- attention phase B: exclusive prefix over chunks ----
__global__ __launch_bounds__(256) void k_attnB(const float* __restrict__ G,
                                               float* __restrict__ Mem) {
  int h = blockIdx.x, tid = threadIdx.x;     // each thread: 16 of 4096 entries
  float4 m[4] = {};
  for (int c = 0; c < NC; c++) {
    size_t off = ((size_t)c * H_ + h) * (HD_ * HD_) + (size_t)tid * 16;
    float4* Mp = (float4*)(Mem + off);
    const float4* Gp = (const float4*)(G + off);
#pragma unroll
    for (int j = 0; j < 4; j++) Mp[j] = m[j];
#pragma unroll
    for (int j = 0; j < 4; j++) {
      float4 gv = Gp[j];
      m[j].x += gv.x; m[j].y += gv.y; m[j].z += gv.z; m[j].w += gv.w;
    }
  }
}

// ---- attention phase C: y = q @ Mem^T + causal(QK^T)@V * 0.5 ----
__global__ __launch_bounds__(128) void k_attnC(
    const unsigned short* __restrict__ qbuf, const unsigned short* __restrict__ kbuf,
    const unsigned short* __restrict__ vbuf, const float* __restrict__ Mem,
    unsigned short* __restrict__ ybuf) {
  int c = blockIdx.x, h = blockIdx.y;
  __shared__ __align__(16) float Ks[CROWS][HD_ + 4];
  __shared__ __align__(16) float Vs[CROWS][HD_ + 4];
  __shared__ __align__(16) float Ms[HD_ * HD_];
  int tid = threadIdx.x;                     // 128 threads: one per row
#pragma unroll
  for (int it = 0; it < 8; it++) {
    int gi = it * 128 + tid;
    int r = gi >> 3, c8 = gi & 7;
    int bb = r & 1, tt = c * CCH + (r >> 1);
    size_t goff = ((size_t)bb * T_ + tt) * D_ + h * HD_ + c8 * 8;
    uint4 kv = *(const uint4*)(kbuf + goff);
    uint4 vv = *(const uint4*)(vbuf + goff);
    unpack8(kv, &Ks[r][c8 * 8]);
    unpack8(vv, &Vs[r][c8 * 8]);
  }
  {
    const float4* Mp = (const float4*)(Mem + ((size_t)c * H_ + h) * (HD_ * HD_));
    float4* Msp = (float4*)Ms;
#pragma unroll
    for (int i = 0; i < 8; i++) Msp[i * 128 + tid] = Mp[i * 128 + tid];
  }
  __syncthreads();

  int r = tid, bb = r & 1, tl = r >> 1;
  const unsigned short* qp = qbuf + ((size_t)bb * T_ + c * CCH + tl) * D_ + h * HD_;
  float q[HD_];
#pragma unroll
  for (int i = 0; i < 8; i++) unpack8(*(const uint4*)(qp + i * 8), &q[i * 8]);

  float y[HD_];
#pragma unroll
  for (int d = 0; d < HD_; d++) {            // y = Ms @ q  (broadcast LDS reads)
    float s = 0.f;
    const float4* Mr = (const float4*)(Ms + d * HD_);
#pragma unroll
    for (int k4 = 0; k4 < 16; k4++) {
      float4 mv = Mr[k4];
      s += mv.x * q[k4 * 4] + mv.y * q[k4 * 4 + 1] + mv.z * q[k4 * 4 + 2] + mv.w * q[k4 * 4 + 3];
    }
    y[d] = s;
  }

  int smax = ((tid >> 6) + 1) * 64;          // wave0: 64 keys, wave1: 128 keys
  for (int s = 0; s < smax; s++) {
    const float4* Kr = (const float4*)(&Ks[s][0]);
    float sc = 0.f;
#pragma unroll
    for (int k4 = 0; k4 < 16; k4++) {
      float4 kv = Kr[k4];
      sc += kv.x * q[k4 * 4] + kv.y * q[k4 * 4 + 1] + kv.z * q[k4 * 4 + 2] + kv.w * q[k4 * 4 + 3];
    }
    sc *= 0.5f;
    if ((s >> 1) <= tl) {
      const float4* Vr = (const float4*)(&Vs[s][0]);
#pragma unroll
      for (int d4 = 0; d4 < 16; d4++) {
        float4 vv = Vr[d4];
        y[d4 * 4]     += sc * vv.x;
        y[d4 * 4 + 1] += sc * vv.y;
        y[d4 * 4 + 2] += sc * vv.z;
        y[d4 * 4 + 3] += sc * vv.w;
      }
    }
  }
  unsigned short* yp = ybuf + ((size_t)bb * T_ + c * CCH + tl) * D_ + h * HD_;
#pragma unroll
  for (int i = 0; i < 32; i++) {
    uint32_t pk = (uint32_t)f2b(y[2 * i]) | ((uint32_t)f2b(y[2 * i + 1]) << 16);
    ((uint32_t*)yp)[i] = pk;
  }
}

extern "C" void kernel_launch(void* const* d_in, const int* in_sizes, int n_in,
                              void* d_out, int out_size, void* d_ws, size_t ws_size,
                              hipStream_t stream) {
  (void)in_sizes; (void)n_in; (void)out_size; (void)ws_size;
  const float* emb  = (const float*)d_in[0];
  const float* pos  = (const float*)d_in[1];
  const float* ln1g = (const float*)d_in[2];
  const float* ln1b = (const float*)d_in[3];
  const float* Wq   = (const float*)d_in[4];
  const float* Wk   = (const float*)d_in[5];
  const float* Wv   = (const float*)d_in[6];
  const float* Wo   = (const float*)d_in[7];
  const float* ln2g = (const float*)d_in[8];
  const float* ln2b = (const float*)d_in[9];
  const float* W1   = (const float*)d_in[10];
  const float* b1   = (const float*)d_in[11];
  const float* W2   = (const float*)d_in[12];
  const float* b2   = (const float*)d_in[13];
  const float* lnfg = (const float*)d_in[14];
  const float* lnfb = (const float*)d_in[15];
  const int*   ids  = (const int*)d_in[16];

  char* w = (char*)d_ws;
  size_t off = 0;
  auto alloc = [&](size_t bytes) -> void* {
    void* p = w + off; off += (bytes + 255) & ~(size_t)255; return p;
  };
  const size_t DD = (size_t)D_ * D_;
  unsigned short* WqkvT = (unsigned short*)alloc(3ull * L_ * DD * 2);
  unsigned short* WoT   = (unsigned short*)alloc((size_t)L_ * DD * 2);
  unsigned short* W1T   = (unsigned short*)alloc((size_t)L_ * NL_ * D_ * HID_ * 2);
  unsigned short* W2cat = (unsigned short*)alloc((size_t)L_ * D_ * NL_ * HID_ * 2);
  unsigned short* embB  = (unsigned short*)alloc((size_t)V_ * D_ * 2);
  float* bsum           = (float*)alloc((size_t)L_ * D_ * 4);
  float* x              = (float*)alloc((size_t)NROW * D_ * 4);
  unsigned short* h     = (unsigned short*)alloc((size_t)NROW * D_ * 2);
  unsigned short* qkv   = (unsigned short*)alloc(3ull * NROW * D_ * 2);
  unsigned short* ybuf  = (unsigned short*)alloc((size_t)NROW * D_ * 2);
  unsigned short* hmid  = (unsigned short*)alloc((size_t)NROW * NL_ * HID_ * 2);
  float* G              = (float*)alloc((size_t)NC * H_ * HD_ * HD_ * 4);
  float* Mem            = (float*)alloc((size_t)NC * H_ * HD_ * HD_ * 4);

  dim3 blk(256);
  // weight prep (every call; deterministic)
  k_transpose_cvt<<<dim3(16, 16, L_), blk, 0, stream>>>(Wq, WqkvT + 0 * L_ * DD, D_, D_);
  k_transpose_cvt<<<dim3(16, 16, L_), blk, 0, stream>>>(Wk, WqkvT + 1 * L_ * DD, D_, D_);
  k_transpose_cvt<<<dim3(16, 16, L_), blk, 0, stream>>>(Wv, WqkvT + 2 * L_ * DD, D_, D_);
  k_transpose_cvt<<<dim3(16, 16, L_), blk, 0, stream>>>(Wo, WoT, D_, D_);
  k_transpose_cvt<<<dim3(HID_ / 32, D_ / 32, L_ * NL_), blk, 0, stream>>>(W1, W1T, D_, HID_);
  k_transpose_w2<<<dim3(D_ / 32, HID_ / 32, L_ * NL_), blk, 0, stream>>>(W2, W2cat);
  k_cvt<<<dim3(V_ * D_ / 1024), blk, 0, stream>>>(emb, embB);
  k_bsum<<<dim3(L_), dim3(512), 0, stream>>>(b2, bsum);

  k_embed<<<dim3(NROW * D_ / 4 / 256), blk, 0, stream>>>(emb, pos, ids, x);

  unsigned short* qb = qkv;
  unsigned short* kb = qkv + (size_t)NROW * D_;
  unsigned short* vb = qkv + 2ull * NROW * D_;

  for (int l = 0; l < L_; l++) {
    k_ln<<<dim3(NROW), dim3(128), 0, stream>>>(x, ln1g + l * D_, ln1b + l * D_, h);
    k_gemm<E_BF16><<<dim3(D_ / BN, NROW / BM, 3), blk, 0, stream>>>(
        h, WqkvT + l * DD, bsum, qkv, D_, D_, D_, (long)(L_ * DD),
        (long)((size_t)NROW * D_), 0);
    k_attnA<<<dim3(NC, H_), blk, 0, stream>>>(kb, vb, G);
    k_attnB<<<dim3(H_), blk, 0, stream>>>(G, Mem);
    k_attnC<<<dim3(NC, H_), dim3(128), 0, stream>>>(qb, kb, vb, Mem, ybuf);
    k_gemm<E_RES><<<dim3(D_ / BN, NROW / BM, 1), blk, 0, stream>>>(
        ybuf, WoT + l * DD, x, x, D_, D_, D_, 0, 0, 0);
    k_ln<<<dim3(NROW), dim3(128), 0, stream>>>(x, ln2g + l * D_, ln2b + l * D_, h);
    k_gemm<E_GELU><<<dim3(HID_ / BN, NROW / BM, NL_), blk, 0, stream>>>(
        h, W1T + (size_t)l * NL_ * D_ * HID_, b1 + (size_t)l * NL_ * HID_, hmid,
        D_, HID_, NL_ * HID_, (long)((size_t)D_ * HID_), (long)HID_, HID_);
    k_gemm<E_CMS><<<dim3(D_ / BN, NROW / BM, 1), blk, 0, stream>>>(
        hmid, W2cat + (size_t)l * D_ * NL_ * HID_, bsum + l * D_, x,
        NL_ * HID_, D_, D_, 0, 0, 0);
  }
  k_ln<<<dim3(NROW), dim3(128), 0, stream>>>(x, lnfg, lnfb, h);
  k_gemm<E_F32><<<dim3(V_ / BN, NROW / BM, 1), blk, 0, stream>>>(
      h, embB, bsum, d_out, D_, V_, V_, 0, 0, 0);
}

// Round 5
// 1262.808 us; speedup vs baseline: 2.0838x; 1.9740x over previous
//
#include <hip/hip_runtime.h>
#include <stdint.h>

// ---- problem constants ----
#define B_ 2
#define T_ 2048
#define D_ 512
#define H_ 8
#define HD_ 64
#define V_ 32000
#define L_ 4
#define NL_ 3
#define HID_ 2048
#define NROW 4096          // B*T
#define CCH 64             // chunk timesteps
#define CROWS 128          // rows per chunk (CCH*B)
#define NC 32              // T/CCH
#define EPS_ 1e-5f

typedef __attribute__((ext_vector_type(8))) __bf16 bf16x8;
typedef __attribute__((ext_vector_type(4))) float f32x4;

__device__ __forceinline__ float b2f(unsigned short u) {
  union { uint32_t i; float f; } v; v.i = ((uint32_t)u) << 16; return v.f;
}
__device__ __forceinline__ unsigned short f2b(float f) {
  union { float f; uint32_t i; } v; v.f = f;
  uint32_t u = v.i;
  u += 0x7fffu + ((u >> 16) & 1u);   // RNE
  return (unsigned short)(u >> 16);
}

// ================= mega-prep: all weight conversion + embed in ONE dispatch ==
// sections (blocks): [0,4096) qkvo-transpose, [4096,16384) W1T,
// [16384,28672) W2cat, [28672,44672) emb cvt, [44672,46720) embed,
// [46720,46728) bsum.  Total 46728.
__global__ __launch_bounds__(256) void k_prep(
    const float* __restrict__ emb, const float* __restrict__ pos,
    const int* __restrict__ ids,
    const float* __restrict__ Wq, const float* __restrict__ Wk,
    const float* __restrict__ Wv, const float* __restrict__ Wo,
    const float* __restrict__ W1, const float* __restrict__ W2,
    const float* __restrict__ b2,
    unsigned short* __restrict__ WqkvT, unsigned short* __restrict__ WoT,
    unsigned short* __restrict__ W1T, unsigned short* __restrict__ W2cat,
    unsigned short* __restrict__ embB, float* __restrict__ bsum,
    float* __restrict__ x) {
  int bid = blockIdx.x, tid = threadIdx.x;
  __shared__ float tile[32][33];
  int tx = tid & 31, ty = tid >> 5;
  if (bid < 4096) {                       // Wq/Wk/Wv (z=l*3+m) + Wo transpose
    int z = bid >> 8, r = bid & 255;
    int bx = (r & 15) * 32, by = (r >> 4) * 32;
    const float* in; unsigned short* out;
    if (z < 12) {
      int l = z / 3, m = z - l * 3;
      in = (m == 0 ? Wq : m == 1 ? Wk : Wv) + (size_t)l * D_ * D_;
      out = WqkvT + (size_t)z * D_ * D_;
    } else {
      in = Wo + (size_t)(z - 12) * D_ * D_;
      out = WoT + (size_t)(z - 12) * D_ * D_;
    }
#pragma unroll
    for (int i = 0; i < 4; i++)
      tile[ty + 8 * i][tx] = in[(size_t)(by + ty + 8 * i) * D_ + bx + tx];
    __syncthreads();
#pragma unroll
    for (int i = 0; i < 4; i++)
      out[(size_t)(bx + ty + 8 * i) * D_ + by + tx] = f2b(tile[tx][ty + 8 * i]);
  } else if (bid < 16384) {               // W1 [z][512][2048] -> W1T [z][2048][512]
    int s = bid - 4096;
    int z = s >> 10, r = s & 1023;
    int bx = (r & 63) * 32, by = (r >> 6) * 32;
    const float* in = W1 + (size_t)z * D_ * HID_;
    unsigned short* out = W1T + (size_t)z * HID_ * D_;
#pragma unroll
    for (int i = 0; i < 4; i++)
      tile[ty + 8 * i][tx] = in[(size_t)(by + ty + 8 * i) * HID_ + bx + tx];
    __syncthreads();
#pragma unroll
    for (int i = 0; i < 4; i++)
      out[(size_t)(bx + ty + 8 * i) * D_ + by + tx] = f2b(tile[tx][ty + 8 * i]);
  } else if (bid < 28672) {               // W2 [z][2048][512] -> W2cat[l][d][n*2048+k]
    int s = bid - 16384;
    int z = s >> 10, r = s & 1023;
    int l = z / 3, n = z - l * 3;
    int bx = (r & 15) * 32, by = (r >> 4) * 32;   // bx: d, by: k
    const float* in = W2 + (size_t)z * HID_ * D_;
#pragma unroll
    for (int i = 0; i < 4; i++)
      tile[ty + 8 * i][tx] = in[(size_t)(by + ty + 8 * i) * D_ + bx + tx];
    __syncthreads();
#pragma unroll
    for (int i = 0; i < 4; i++)
      W2cat[((size_t)l * D_ + bx + ty + 8 * i) * (NL_ * HID_) + n * HID_ + by + tx] =
          f2b(tile[tx][ty + 8 * i]);
  } else if (bid < 44672) {               // emb f32 -> bf16 (16000 blocks x 1024 elem)
    int s = bid - 28672;
    int base = (s * 256 + tid) * 4;
    float4 v = *(const float4*)(emb + base);
    unsigned short o[4] = { f2b(v.x), f2b(v.y), f2b(v.z), f2b(v.w) };
    *(uint2*)(embB + base) = *(const uint2*)o;
  } else if (bid < 46720) {               // embedding gather + pos (2048 blocks)
    int s = bid - 44672;
    int i = s * 256 + tid;                // float4 group, [0, NROW*128)
    int row = i >> 7, cg = i & 127;
    int t = row & (T_ - 1);
    int id = ids[row];
    float4 e = ((const float4*)(emb + (size_t)id * D_))[cg];
    float4 p = ((const float4*)(pos + (size_t)t * D_))[cg];
    float4 rr; rr.x = e.x + p.x; rr.y = e.y + p.y; rr.z = e.z + p.z; rr.w = e.w + p.w;
    ((float4*)(x + (size_t)row * D_))[cg] = rr;
  } else {                                // bsum (8 blocks)
    int s = bid - 46720;
    int l = s >> 1, d = (s & 1) * 256 + tid;
    float acc = 0.f;
#pragma unroll
    for (int n = 0; n < NL_; n++) acc += b2[((size_t)l * NL_ + n) * D_ + d];
    bsum[(size_t)l * D_ + d] = acc;
  }
}

// ---- layernorm: f32 row -> bf16 row ----
__global__ __launch_bounds__(128) void k_ln(
    const float* __restrict__ x, const float* __restrict__ g,
    const float* __restrict__ b, unsigned short* __restrict__ out) {
  int row = blockIdx.x;
  int tid = threadIdx.x;
  const float* xr = x + (size_t)row * D_;
  float4 v = ((const float4*)xr)[tid];
  float s = v.x + v.y + v.z + v.w;
#pragma unroll
  for (int o = 32; o >= 1; o >>= 1) s += __shfl_xor(s, o);
  __shared__ float red[2], red2[2];
  int wv = tid >> 6;
  if ((tid & 63) == 0) red[wv] = s;
  __syncthreads();
  float mu = (red[0] + red[1]) * (1.f / D_);
  float dx = v.x - mu, dy = v.y - mu, dz = v.z - mu, dw = v.w - mu;
  float s2 = dx * dx + dy * dy + dz * dz + dw * dw;
#pragma unroll
  for (int o = 32; o >= 1; o >>= 1) s2 += __shfl_xor(s2, o);
  if ((tid & 63) == 0) red2[wv] = s2;
  __syncthreads();
  float var = (red2[0] + red2[1]) * (1.f / D_);
  float rs = rsqrtf(var + EPS_);
  float4 gv = ((const float4*)g)[tid];
  float4 bv = ((const float4*)b)[tid];
  unsigned short o4[4] = { f2b(dx * rs * gv.x + bv.x), f2b(dy * rs * gv.y + bv.y),
                           f2b(dz * rs * gv.z + bv.z), f2b(dw * rs * gv.w + bv.w) };
  *(uint2*)(out + (size_t)row * D_ + tid * 4) = *(const uint2*)o4;
}

// ================= GEMM templates =================
enum { E_QKV = 0, E_RES = 1, E_GELU = 2, E_CMS = 3, E_F32 = 4 };

// stage a TRx64 bf16 tile (rows*128B), source-side XOR swizzle, gload_lds w16
template <int TR, int NW>
__device__ __forceinline__ void stage_tile(
    const unsigned short* __restrict__ gbase, int ldk, unsigned short* lds,
    int wave, int lane) {
#pragma unroll
  for (int q = 0; q < 4; q++) {
    int Lb = (q * NW + wave) << 10;             // wave-uniform LDS byte base
    int L = Lb + lane * 16;
    int row = L >> 7;
    int colb = (L & 127) ^ ((row & 7) << 4);    // involutive swizzle
    const unsigned short* gsrc = gbase + (size_t)row * ldk + (colb >> 1);
    __builtin_amdgcn_global_load_lds(
        (const __attribute__((address_space(1))) uint32_t*)gsrc,
        (__attribute__((address_space(3))) uint32_t*)(lds + (Lb >> 1)),
        16, 0, 0);
  }
}

// ---- 128x128x64, 4 waves, single-buffer (R2-proven core) ----
template <int EPI>
__global__ __launch_bounds__(256, 4) void k_gemm128(
    const unsigned short* __restrict__ A,   // [M,K] bf16
    const unsigned short* __restrict__ Bt,  // [N,K] bf16
    const float* __restrict__ bias,
    void* __restrict__ Out,
    int K, int N, int ldOut) {
  int lane = threadIdx.x & 63, wave = threadIdx.x >> 6;
  int wm = wave >> 1, wn = wave & 1;
  int bx = blockIdx.x, by = blockIdx.y;

  __shared__ __align__(16) unsigned short As[128 * 64];
  __shared__ __align__(16) unsigned short Bs[128 * 64];

  const unsigned short* Ab = A + (size_t)by * 128 * K;
  const unsigned short* Bb = Bt + (size_t)bx * 128 * K;

  f32x4 acc[4][4] = {};
  int nk = K / 64;
  for (int kt = 0; kt < nk; kt++) {
    stage_tile<128, 4>(Ab + (size_t)kt * 64, K, As, wave, lane);
    stage_tile<128, 4>(Bb + (size_t)kt * 64, K, Bs, wave, lane);
    __syncthreads();
    const char* Ac = (const char*)As;
    const char* Bc = (const char*)Bs;
#pragma unroll
    for (int kk = 0; kk < 2; kk++) {
      bf16x8 af[4], bfr[4];
#pragma unroll
      for (int mt = 0; mt < 4; mt++) {
        int row = wm * 64 + mt * 16 + (lane & 15);
        int off = ((row << 7) | (kk * 64 + ((lane >> 4) << 4))) ^ ((row & 7) << 4);
        af[mt] = *(const bf16x8*)(Ac + off);
      }
#pragma unroll
      for (int nt = 0; nt < 4; nt++) {
        int row = wn * 64 + nt * 16 + (lane & 15);
        int off = ((row << 7) | (kk * 64 + ((lane >> 4) << 4))) ^ ((row & 7) << 4);
        bfr[nt] = *(const bf16x8*)(Bc + off);
      }
#pragma unroll
      for (int mt = 0; mt < 4; mt++)
#pragma unroll
        for (int nt = 0; nt < 4; nt++)
          acc[mt][nt] = __builtin_amdgcn_mfma_f32_16x16x32_bf16(
              af[mt], bfr[nt], acc[mt][nt], 0, 0, 0);
    }
    __syncthreads();
  }

  int gm = by * 128 + wm * 64;
  int gn = bx * 128 + wn * 64;
#pragma unroll
  for (int mt = 0; mt < 4; mt++) {
#pragma unroll
    for (int nt = 0; nt < 4; nt++) {
      int m0 = gm + mt * 16 + ((lane >> 4) << 2);
      int n = gn + nt * 16 + (lane & 15);
#pragma unroll
      for (int j = 0; j < 4; j++) {
        float v = acc[mt][nt][j];
        int m = m0 + j;
        if constexpr (EPI == E_QKV) {          // N=1536 -> qkv[z][row][col]
          int zq = n >> 9, col = n & 511;
          ((unsigned short*)Out)[((size_t)zq * NROW + m) * D_ + col] = f2b(v);
        } else if constexpr (EPI == E_RES) {   // x = resid + v
          size_t idx = (size_t)m * ldOut + n;
          ((float*)Out)[idx] = bias[idx] + v;
        } else if constexpr (EPI == E_CMS) {   // x += (v + bsum)/3
          size_t idx = (size_t)m * ldOut + n;
          ((float*)Out)[idx] += (v + bias[n]) * (1.f / 3.f);
        }
      }
    }
  }
}

// ---- 256x256x64, 8 waves, single-buffer ----
template <int EPI>
__global__ __launch_bounds__(512, 1) void k_gemm256(
    const unsigned short* __restrict__ A,
    const unsigned short* __restrict__ Bt,
    const float* __restrict__ bias,
    void* __restrict__ Out,
    int K, int N, int ldOut) {
  int lane = threadIdx.x & 63, wave = threadIdx.x >> 6;   // 8 waves
  int wm = wave >> 2, wn = wave & 3;
  int bx = blockIdx.x, by = blockIdx.y;
  if constexpr (EPI == E_F32) {
    // supertile remap: 25 bx x 16 by groups for B-panel L2/L3 reuse (gridDim.x=125)
    int lin = blockIdx.y * 125 + blockIdx.x;
    int seg = lin / 400, rem = lin % 400;
    bx = seg * 25 + rem % 25;  by = rem / 25;
  }

  __shared__ __align__(16) unsigned short As[256 * 64];
  __shared__ __align__(16) unsigned short Bs[256 * 64];

  const unsigned short* Ab = A + (size_t)by * 256 * K;
  const unsigned short* Bb = Bt + (size_t)bx * 256 * K;

  f32x4 acc[8][4] = {};
  int nk = K / 64;
  for (int kt = 0; kt < nk; kt++) {
    stage_tile<256, 8>(Ab + (size_t)kt * 64, K, As, wave, lane);
    stage_tile<256, 8>(Bb + (size_t)kt * 64, K, Bs, wave, lane);
    __syncthreads();
    const char* Ac = (const char*)As;
    const char* Bc = (const char*)Bs;
#pragma unroll
    for (int kk = 0; kk < 2; kk++) {
      bf16x8 af[8], bfr[4];
#pragma unroll
      for (int mt = 0; mt < 8; mt++) {
        int row = wm * 128 + mt * 16 + (lane & 15);
        int off = ((row << 7) | (kk * 64 + ((lane >> 4) << 4))) ^ ((row & 7) << 4);
        af[mt] = *(const bf16x8*)(Ac + off);
      }
#pragma unroll
      for (int nt = 0; nt < 4; nt++) {
        int row = wn * 64 + nt * 16 + (lane & 15);
        int off = ((row << 7) | (kk * 64 + ((lane >> 4) << 4))) ^ ((row & 7) << 4);
        bfr[nt] = *(const bf16x8*)(Bc + off);
      }
#pragma unroll
      for (int mt = 0; mt < 8; mt++)
#pragma unroll
        for (int nt = 0; nt < 4; nt++)
          acc[mt][nt] = __builtin_amdgcn_mfma_f32_16x16x32_bf16(
              af[mt], bfr[nt], acc[mt][nt], 0, 0, 0);
    }
    __syncthreads();
  }

  int gm = by * 256 + wm * 128;
  int gn = bx * 256 + wn * 64;
#pragma unroll
  for (int mt = 0; mt < 8; mt++) {
#pragma unroll
    for (int nt = 0; nt < 4; nt++) {
      int m0 = gm + mt * 16 + ((lane >> 4) << 2);
      int n = gn + nt * 16 + (lane & 15);
#pragma unroll
      for (int j = 0; j < 4; j++) {
        float v = acc[mt][nt][j];
        size_t idx = (size_t)(m0 + j) * ldOut + n;
        if constexpr (EPI == E_GELU) {
          v += bias[n];
          float u2 = 1.5957691216057308f * (v + 0.044715f * v * v * v);
          float sg = 1.f / (1.f + __expf(-u2));   // tanh-approx GELU
          ((unsigned short*)Out)[idx] = f2b(v * sg);
        } else {                                  // E_F32 (head)
          ((float*)Out)[idx] = v;
        }
      }
    }
  }
}

// ---- attention phase A: G[c,h,d,k] = 0.5 * sum_rows v_d * k_k ----
__device__ __forceinline__ void unpack8f(uint4 u, float* dst) {
  dst[0] = b2f((unsigned short)(u.x & 0xffff)); dst[1] = b2f((unsigned short)(u.x >> 16));
  dst[2] = b2f((unsigned short)(u.y & 0xffff)); dst[3] = b2f((unsigned short)(u.y >> 16));
  dst[4] = b2f((unsigned short)(u.z & 0xffff)); dst[5] = b2f((unsigned short)(u.z >> 16));
  dst[6] = b2f((unsigned short)(u.w & 0xffff)); dst[7] = b2f((unsigned short)(u.w >> 16));
}

__global__ __launch_bounds__(256) void k_attnA(
    const unsigned short* __restrict__ kbuf, const unsigned short* __restrict__ vbuf,
    float* __restrict__ G) {
  int c = blockIdx.x, h = blockIdx.y;
  __shared__ __align__(16) float Ks[CROWS][HD_];
  __shared__ __align__(16) float Vs[CROWS][HD_];
  int tid = threadIdx.x;
#pragma unroll
  for (int it = 0; it < 4; it++) {
    int gi = it * 256 + tid;
    int r = gi >> 3, c8 = gi & 7;
    int bb = r & 1, tt = c * CCH + (r >> 1);
    size_t goff = ((size_t)bb * T_ + tt) * D_ + h * HD_ + c8 * 8;
    uint4 kv = *(const uint4*)(kbuf + goff);
    uint4 vv = *(const uint4*)(vbuf + goff);
    unpack8f(kv, &Ks[r][c8 * 8]);
    unpack8f(vv, &Vs[r][c8 * 8]);
  }
  __syncthreads();
  int d = tid & 63, kb = (tid >> 6) * 16;     // kb wave-uniform -> broadcast reads
  float acc[16] = {};
  for (int r = 0; r < CROWS; r++) {
    float vd = Vs[r][d];
#pragma unroll
    for (int j = 0; j < 16; j++) acc[j] += vd * Ks[r][kb + j];
  }
  float* Gp = G + (((size_t)c * H_ + h) * HD_ + d) * HD_ + kb;
#pragma unroll
  for (int j = 0; j < 16; j++) Gp[j] = 0.5f * acc[j];
}

// ---- attention phase B: exclusive prefix over chunks (128 blocks) ----
__global__ __launch_bounds__(256) void k_attnB(const float* __restrict__ G,
                                               float* __restrict__ Mem) {
  int h = blockIdx.x >> 4, seg = blockIdx.x & 15;
  int idx = seg * 256 + threadIdx.x;
  float m = 0.f;
  for (int c = 0; c < NC; c++) {
    size_t off = ((size_t)c * H_ + h) * (HD_ * HD_) + idx;
    Mem[off] = m;
    m += G[off];
  }
}

// ---- attention phase C (MFMA): Y = Q@Mem^T (hi/lo bf16) + causal(QK^T*0.5)@V ----
__global__ __launch_bounds__(256) void k_attnC(
    const unsigned short* __restrict__ qbuf, const unsigned short* __restrict__ kbuf,
    const unsigned short* __restrict__ vbuf, const float* __restrict__ Mem,
    unsigned short* __restrict__ ybuf) {
  int c = blockIdx.x, h = blockIdx.y;
  __shared__ __align__(16) unsigned short smem[32768];   // 64 KB, all XOR-swizzled
  unsigned short* Qs  = smem;            // 128x64
  unsigned short* Ksh = smem + 8192;     // 128x64
  unsigned short* Vt  = smem + 16384;    // 64x128 (V transposed)
  unsigned short* Mhi = smem + 24576;    // 64x64
  unsigned short* Mlo = smem + 28672;    // 64x64
  unsigned short* Ps  = smem;            // 128x128 overlays Qs+Ksh exactly

  int tid = threadIdx.x, lane = tid & 63, w = tid >> 6;
#pragma unroll
  for (int it = 0; it < 4; it++) {
    int gi = it * 256 + tid;
    int r = gi >> 3, g8 = gi & 7;
    int bb = r & 1, tt = c * CCH + (r >> 1);
    size_t go = ((size_t)bb * T_ + tt) * D_ + h * HD_ + g8 * 8;
    int qc = (g8 * 8) ^ ((r & 7) << 3);
    *(uint4*)(Qs + r * 64 + qc) = *(const uint4*)(qbuf + go);
    *(uint4*)(Ksh + r * 64 + qc) = *(const uint4*)(kbuf + go);
    uint4 vv = *(const uint4*)(vbuf + go);
    const unsigned short* vp = (const unsigned short*)&vv;
#pragma unroll
    for (int j = 0; j < 8; j++) {
      int d = g8 * 8 + j;
      int t = (d & 7) ^ (d >> 3);
      Vt[d * 128 + (r ^ (t << 3))] = vp[j];
    }
  }
  {
    const float* Mp = Mem + (((size_t)c * H_ + h) << 12);
#pragma unroll
    for (int it = 0; it < 16; it++) {
      int i = it * 256 + tid;
      int d = i >> 6, k = i & 63;
      float m = Mp[i];
      unsigned short hi = f2b(m);
      float lo = m - b2f(hi);
      int col = k ^ ((d & 7) << 3);
      Mhi[d * 64 + col] = hi;
      Mlo[d * 64 + col] = f2b(lo);
    }
  }
  __syncthreads();

  int row0 = w * 32;
  f32x4 sacc[2][8] = {};
  f32x4 yacc[2][4] = {};
#pragma unroll
  for (int kk = 0; kk < 2; kk++) {
    bf16x8 aq[2];
#pragma unroll
    for (int mt = 0; mt < 2; mt++) {
      int row = row0 + mt * 16 + (lane & 15);
      aq[mt] = *(const bf16x8*)(Qs + row * 64 +
                ((kk * 32 + ((lane >> 4) << 3)) ^ ((row & 7) << 3)));
    }
#pragma unroll
    for (int nt = 0; nt < 8; nt++) {
      int row = nt * 16 + (lane & 15);
      bf16x8 bk = *(const bf16x8*)(Ksh + row * 64 +
                ((kk * 32 + ((lane >> 4) << 3)) ^ ((row & 7) << 3)));
#pragma unroll
      for (int mt = 0; mt < 2; mt++)
        sacc[mt][nt] = __builtin_amdgcn_mfma_f32_16x16x32_bf16(aq[mt], bk,
                                                               sacc[mt][nt], 0, 0, 0);
    }
#pragma unroll
    for (int nt = 0; nt < 4; nt++) {
      int row = nt * 16 + (lane & 15);
      int off = row * 64 + ((kk * 32 + ((lane >> 4) << 3)) ^ ((row & 7) << 3));
      bf16x8 bh = *(const bf16x8*)(Mhi + off);
      bf16x8 bl = *(const bf16x8*)(Mlo + off);
#pragma unroll
      for (int mt = 0; mt < 2; mt++) {
        yacc[mt][nt] = __builtin_amdgcn_mfma_f32_16x16x32_bf16(aq[mt], bh,
                                                               yacc[mt][nt], 0, 0, 0);
        yacc[mt][nt] = __builtin_amdgcn_mfma_f32_16x16x32_bf16(aq[mt], bl,
                                                               yacc[mt][nt], 0, 0, 0);
      }
    }
  }
  __syncthreads();   // everyone done reading Qs/Ksh before Ps overlay

  // masked, scaled P -> LDS (bf16). row (b,t)-interleaved: time = idx>>1
#pragma unroll
  for (int mt = 0; mt < 2; mt++)
#pragma unroll
    for (int nt = 0; nt < 8; nt++)
#pragma unroll
      for (int j = 0; j < 4; j++) {
        int qr = row0 + mt * 16 + ((lane >> 4) << 2) + j;
        int ks = nt * 16 + (lane & 15);
        float v = ((ks >> 1) <= (qr >> 1)) ? sacc[mt][nt][j] * 0.5f : 0.f;
        Ps[qr * 128 + (ks ^ ((qr & 7) << 3))] = f2b(v);
      }
  __syncthreads();

  // PV: each wave owns its 32 q-rows; key blocks kb <= w are (partially) unmasked
  for (int kb = 0; kb <= w; kb++) {
    bf16x8 ap[2];
#pragma unroll
    for (int mt = 0; mt < 2; mt++) {
      int row = row0 + mt * 16 + (lane & 15);
      ap[mt] = *(const bf16x8*)(Ps + row * 128 +
                ((kb * 32 + ((lane >> 4) << 3)) ^ ((row & 7) << 3)));
    }
#pragma unroll
    for (int nt = 0; nt < 4; nt++) {
      int d = nt * 16 + (lane & 15);
      int t = (d & 7) ^ (d >> 3);
      int gb = (kb * 32 + ((lane >> 4) << 3)) ^ (t << 3);
      bf16x8 bv = *(const bf16x8*)(Vt + d * 128 + gb);
#pragma unroll
      for (int mt = 0; mt < 2; mt++)
        yacc[mt][nt] = __builtin_amdgcn_mfma_f32_16x16x32_bf16(ap[mt], bv,
                                                               yacc[mt][nt], 0, 0, 0);
    }
  }

#pragma unroll
  for (int mt = 0; mt < 2; mt++)
#pragma unroll
    for (int nt = 0; nt < 4; nt++)
#pragma unroll
      for (int j = 0; j < 4; j++) {
        int qr = row0 + mt * 16 + ((lane >> 4) << 2) + j;
        int d = nt * 16 + (lane & 15);
        int bb = qr & 1, tl = qr >> 1;
        ybuf[((size_t)bb * T_ + c * CCH + tl) * D_ + h * HD_ + d] =
            f2b(yacc[mt][nt][j]);
      }
}

extern "C" void kernel_launch(void* const* d_in, const int* in_sizes, int n_in,
                              void* d_out, int out_size, void* d_ws, size_t ws_size,
                              hipStream_t stream) {
  (void)in_sizes; (void)n_in; (void)out_size; (void)ws_size;
  const float* emb  = (const float*)d_in[0];
  const float* pos  = (const float*)d_in[1];
  const float* ln1g = (const float*)d_in[2];
  const float* ln1b = (const float*)d_in[3];
  const float* Wq   = (const float*)d_in[4];
  const float* Wk   = (const float*)d_in[5];
  const float* Wv   = (const float*)d_in[6];
  const float* Wo   = (const float*)d_in[7];
  const float* ln2g = (const float*)d_in[8];
  const float* ln2b = (const float*)d_in[9];
  const float* W1   = (const float*)d_in[10];
  const float* b1   = (const float*)d_in[11];
  const float* W2   = (const float*)d_in[12];
  const float* b2   = (const float*)d_in[13];
  const float* lnfg = (const float*)d_in[14];
  const float* lnfb = (const float*)d_in[15];
  const int*   ids  = (const int*)d_in[16];

  char* w = (char*)d_ws;
  size_t off = 0;
  auto alloc = [&](size_t bytes) -> void* {
    void* p = w + off; off += (bytes + 255) & ~(size_t)255; return p;
  };
  const size_t DD = (size_t)D_ * D_;
  unsigned short* WqkvT = (unsigned short*)alloc(12ull * DD * 2);  // [l*3+m][D][D]
  unsigned short* WoT   = (unsigned short*)alloc(4ull * DD * 2);
  unsigned short* W1T   = (unsigned short*)alloc((size_t)L_ * NL_ * HID_ * D_ * 2);
  unsigned short* W2cat = (unsigned short*)alloc((size_t)L_ * D_ * NL_ * HID_ * 2);
  unsigned short* embB  = (unsigned short*)alloc((size_t)V_ * D_ * 2);
  float* bsum           = (float*)alloc((size_t)L_ * D_ * 4);
  float* x              = (float*)alloc((size_t)NROW * D_ * 4);
  unsigned short* h     = (unsigned short*)alloc((size_t)NROW * D_ * 2);
  unsigned short* qkv   = (unsigned short*)alloc(3ull * NROW * D_ * 2);
  unsigned short* ybuf  = (unsigned short*)alloc((size_t)NROW * D_ * 2);
  float* G              = (float*)alloc((size_t)NC * H_ * HD_ * HD_ * 4);
  float* Mem            = (float*)alloc((size_t)NC * H_ * HD_ * HD_ * 4);
  unsigned short* hmid  = (unsigned short*)alloc((size_t)NROW * NL_ * HID_ * 2);

  dim3 blk(256);
  k_prep<<<dim3(46728), blk, 0, stream>>>(emb, pos, ids, Wq, Wk, Wv, Wo, W1, W2, b2,
                                          WqkvT, WoT, W1T, W2cat, embB, bsum, x);

  unsigned short* qb = qkv;
  unsigned short* kb = qkv + (size_t)NROW * D_;
  unsigned short* vb = qkv + 2ull * NROW * D_;

  for (int l = 0; l < L_; l++) {
    k_ln<<<dim3(NROW), dim3(128), 0, stream>>>(x, ln1g + l * D_, ln1b + l * D_, h);
    k_gemm128<E_QKV><<<dim3(12, 32), blk, 0, stream>>>(
        h, WqkvT + (size_t)l * 3 * DD, bsum, qkv, D_, 3 * D_, D_);
    k_attnA<<<dim3(NC, H_), blk, 0, stream>>>(kb, vb, G);
    k_attnB<<<dim3(H_ * 16), blk, 0, stream>>>(G, Mem);
    k_attnC<<<dim3(NC, H_), blk, 0, stream>>>(qb, kb, vb, Mem, ybuf);
    k_gemm128<E_RES><<<dim3(4, 32), blk, 0, stream>>>(
        ybuf, WoT + (size_t)l * DD, x, x, D_, D_, D_);
    k_ln<<<dim3(NROW), dim3(128), 0, stream>>>(x, ln2g + l * D_, ln2b + l * D_, h);
    k_gemm256<E_GELU><<<dim3(24, 16), dim3(512), 0, stream>>>(
        h, W1T + (size_t)l * NL_ * HID_ * D_, b1 + (size_t)l * NL_ * HID_, hmid,
        D_, NL_ * HID_, NL_ * HID_);
    k_gemm128<E_CMS><<<dim3(4, 32), blk, 0, stream>>>(
        hmid, W2cat + (size_t)l * D_ * NL_ * HID_, bsum + l * D_, x,
        NL_ * HID_, D_, D_);
  }
  k_ln<<<dim3(NROW), dim3(128), 0, stream>>>(x, lnfg, lnfb, h);
  k_gemm256<E_F32><<<dim3(125, 16), dim3(512), 0, stream>>>(
      h, embB, bsum, d_out, D_, V_, V_);
}

// Round 6
// 919.168 us; speedup vs baseline: 2.8629x; 1.3739x over previous
//
#include <hip/hip_runtime.h>
#include <stdint.h>

// ---- problem constants ----
#define B_ 2
#define T_ 2048
#define D_ 512
#define H_ 8
#define HD_ 64
#define V_ 32000
#define L_ 4
#define NL_ 3
#define HID_ 2048
#define NROW 4096          // B*T
#define CCH 64             // chunk timesteps
#define CROWS 128          // rows per chunk (CCH*B)
#define NC 32              // T/CCH
#define EPS_ 1e-5f

typedef __attribute__((ext_vector_type(8))) __bf16 bf16x8;
typedef __attribute__((ext_vector_type(4))) float f32x4;

__device__ __forceinline__ float b2f(unsigned short u) {
  union { uint32_t i; float f; } v; v.i = ((uint32_t)u) << 16; return v.f;
}
__device__ __forceinline__ unsigned short f2b(float f) {
  union { float f; uint32_t i; } v; v.f = f;
  uint32_t u = v.i;
  u += 0x7fffu + ((u >> 16) & 1u);   // RNE
  return (unsigned short)(u >> 16);
}

// ================= mega-prep: weights + embed + layer-0 LN1 in ONE dispatch ==
// sections (blocks): [0,4096) qkvo-transpose, [4096,16384) W1T,
// [16384,28672) W2cat, [28672,44672) emb cvt, [44672,46720) embed+LN1(l=0),
// [46720,46728) bsum.  Total 46728.
__global__ __launch_bounds__(256) void k_prep(
    const float* __restrict__ emb, const float* __restrict__ pos,
    const int* __restrict__ ids,
    const float* __restrict__ Wq, const float* __restrict__ Wk,
    const float* __restrict__ Wv, const float* __restrict__ Wo,
    const float* __restrict__ W1, const float* __restrict__ W2,
    const float* __restrict__ b2,
    const float* __restrict__ ln1g, const float* __restrict__ ln1b,
    unsigned short* __restrict__ WqkvT, unsigned short* __restrict__ WoT,
    unsigned short* __restrict__ W1T, unsigned short* __restrict__ W2cat,
    unsigned short* __restrict__ embB, float* __restrict__ bsum,
    float* __restrict__ x, unsigned short* __restrict__ h) {
  int bid = blockIdx.x, tid = threadIdx.x;
  __shared__ float tile[32][33];
  __shared__ float red[4], red2[4];
  int tx = tid & 31, ty = tid >> 5;
  if (bid < 4096) {                       // Wq/Wk/Wv (z=l*3+m) + Wo transpose
    int z = bid >> 8, r = bid & 255;
    int bx = (r & 15) * 32, by = (r >> 4) * 32;
    const float* in; unsigned short* out;
    if (z < 12) {
      int l = z / 3, m = z - l * 3;
      in = (m == 0 ? Wq : m == 1 ? Wk : Wv) + (size_t)l * D_ * D_;
      out = WqkvT + (size_t)z * D_ * D_;
    } else {
      in = Wo + (size_t)(z - 12) * D_ * D_;
      out = WoT + (size_t)(z - 12) * D_ * D_;
    }
#pragma unroll
    for (int i = 0; i < 4; i++)
      tile[ty + 8 * i][tx] = in[(size_t)(by + ty + 8 * i) * D_ + bx + tx];
    __syncthreads();
#pragma unroll
    for (int i = 0; i < 4; i++)
      out[(size_t)(bx + ty + 8 * i) * D_ + by + tx] = f2b(tile[tx][ty + 8 * i]);
  } else if (bid < 16384) {               // W1 [z][512][2048] -> W1T [z][2048][512]
    int s = bid - 4096;
    int z = s >> 10, r = s & 1023;
    int bx = (r & 63) * 32, by = (r >> 6) * 32;
    const float* in = W1 + (size_t)z * D_ * HID_;
    unsigned short* out = W1T + (size_t)z * HID_ * D_;
#pragma unroll
    for (int i = 0; i < 4; i++)
      tile[ty + 8 * i][tx] = in[(size_t)(by + ty + 8 * i) * HID_ + bx + tx];
    __syncthreads();
#pragma unroll
    for (int i = 0; i < 4; i++)
      out[(size_t)(bx + ty + 8 * i) * D_ + by + tx] = f2b(tile[tx][ty + 8 * i]);
  } else if (bid < 28672) {               // W2 [z][2048][512] -> W2cat[l][d][n*2048+k]
    int s = bid - 16384;
    int z = s >> 10, r = s & 1023;
    int l = z / 3, n = z - l * 3;
    int bx = (r & 15) * 32, by = (r >> 4) * 32;   // bx: d, by: k
    const float* in = W2 + (size_t)z * HID_ * D_;
#pragma unroll
    for (int i = 0; i < 4; i++)
      tile[ty + 8 * i][tx] = in[(size_t)(by + ty + 8 * i) * D_ + bx + tx];
    __syncthreads();
#pragma unroll
    for (int i = 0; i < 4; i++)
      W2cat[((size_t)l * D_ + bx + ty + 8 * i) * (NL_ * HID_) + n * HID_ + by + tx] =
          f2b(tile[tx][ty + 8 * i]);
  } else if (bid < 44672) {               // emb f32 -> bf16
    int s = bid - 28672;
    int base = (s * 256 + tid) * 4;
    float4 v = *(const float4*)(emb + base);
    unsigned short o[4] = { f2b(v.x), f2b(v.y), f2b(v.z), f2b(v.w) };
    *(uint2*)(embB + base) = *(const uint2*)o;
  } else if (bid < 46720) {               // embed + LN1(layer0): 2 rows per block
    int s = bid - 44672;
    int i = s * 256 + tid;
    int row = i >> 7, cg = i & 127;
    int t = row & (T_ - 1);
    int id = ids[row];
    float4 e = ((const float4*)(emb + (size_t)id * D_))[cg];
    float4 p = ((const float4*)(pos + (size_t)t * D_))[cg];
    float4 xv; xv.x = e.x + p.x; xv.y = e.y + p.y; xv.z = e.z + p.z; xv.w = e.w + p.w;
    ((float4*)(x + (size_t)row * D_))[cg] = xv;
    // LN across the row's 128 threads (2 waves per row)
    float sum = xv.x + xv.y + xv.z + xv.w;
#pragma unroll
    for (int o = 32; o >= 1; o >>= 1) sum += __shfl_xor(sum, o);
    int wv = tid >> 6;
    if ((tid & 63) == 0) red[wv] = sum;
    __syncthreads();
    int wb = (tid >> 7) * 2;
    float mu = (red[wb] + red[wb + 1]) * (1.f / D_);
    float dx = xv.x - mu, dy = xv.y - mu, dz = xv.z - mu, dw = xv.w - mu;
    float s2 = dx * dx + dy * dy + dz * dz + dw * dw;
#pragma unroll
    for (int o = 32; o >= 1; o >>= 1) s2 += __shfl_xor(s2, o);
    if ((tid & 63) == 0) red2[wv] = s2;
    __syncthreads();
    float var = (red2[wb] + red2[wb + 1]) * (1.f / D_);
    float rs = rsqrtf(var + EPS_);
    float4 gv = ((const float4*)ln1g)[cg];
    float4 bv = ((const float4*)ln1b)[cg];
    unsigned short o4[4] = { f2b(dx * rs * gv.x + bv.x), f2b(dy * rs * gv.y + bv.y),
                             f2b(dz * rs * gv.z + bv.z), f2b(dw * rs * gv.w + bv.w) };
    *(uint2*)(h + (size_t)row * D_ + cg * 4) = *(const uint2*)o4;
  } else {                                // bsum
    int s = bid - 46720;
    int l = s >> 1, d = (s & 1) * 256 + tid;
    float acc = 0.f;
#pragma unroll
    for (int n = 0; n < NL_; n++) acc += b2[((size_t)l * NL_ + n) * D_ + d];
    bsum[(size_t)l * D_ + d] = acc;
  }
}

// ---- layernorm (LN2 only): f32 row -> bf16 row ----
__global__ __launch_bounds__(128) void k_ln(
    const float* __restrict__ x, const float* __restrict__ g,
    const float* __restrict__ b, unsigned short* __restrict__ out) {
  int row = blockIdx.x;
  int tid = threadIdx.x;
  const float* xr = x + (size_t)row * D_;
  float4 v = ((const float4*)xr)[tid];
  float s = v.x + v.y + v.z + v.w;
#pragma unroll
  for (int o = 32; o >= 1; o >>= 1) s += __shfl_xor(s, o);
  __shared__ float red[2], red2[2];
  int wv = tid >> 6;
  if ((tid & 63) == 0) red[wv] = s;
  __syncthreads();
  float mu = (red[0] + red[1]) * (1.f / D_);
  float dx = v.x - mu, dy = v.y - mu, dz = v.z - mu, dw = v.w - mu;
  float s2 = dx * dx + dy * dy + dz * dz + dw * dw;
#pragma unroll
  for (int o = 32; o >= 1; o >>= 1) s2 += __shfl_xor(s2, o);
  if ((tid & 63) == 0) red2[wv] = s2;
  __syncthreads();
  float var = (red2[0] + red2[1]) * (1.f / D_);
  float rs = rsqrtf(var + EPS_);
  float4 gv = ((const float4*)g)[tid];
  float4 bv = ((const float4*)b)[tid];
  unsigned short o4[4] = { f2b(dx * rs * gv.x + bv.x), f2b(dy * rs * gv.y + bv.y),
                           f2b(dz * rs * gv.z + bv.z), f2b(dw * rs * gv.w + bv.w) };
  *(uint2*)(out + (size_t)row * D_ + tid * 4) = *(const uint2*)o4;
}

// ---- cms reduce + next LN fused: x += (p0+p1+p2+bsum)/3; h = LN(x) ----
__global__ __launch_bounds__(256) void k_cmsred_ln(
    float* __restrict__ x, const float* __restrict__ parts,
    const float* __restrict__ bsum, const float* __restrict__ g,
    const float* __restrict__ b, unsigned short* __restrict__ h) {
  int bid = blockIdx.x, tid = threadIdx.x;
  int row = bid * 2 + (tid >> 7);
  int cg = tid & 127;
  size_t base = (size_t)row * D_ + cg * 4;
  float4 xv = *(const float4*)(x + base);
  float4 p0 = *(const float4*)(parts + base);
  float4 p1 = *(const float4*)(parts + (size_t)NROW * D_ + base);
  float4 p2 = *(const float4*)(parts + 2ull * NROW * D_ + base);
  float4 bs = *(const float4*)(bsum + cg * 4);
  const float k3 = 1.f / 3.f;
  xv.x += (p0.x + p1.x + p2.x + bs.x) * k3;
  xv.y += (p0.y + p1.y + p2.y + bs.y) * k3;
  xv.z += (p0.z + p1.z + p2.z + bs.z) * k3;
  xv.w += (p0.w + p1.w + p2.w + bs.w) * k3;
  *(float4*)(x + base) = xv;
  // LN across the row's 128 threads
  float sum = xv.x + xv.y + xv.z + xv.w;
#pragma unroll
  for (int o = 32; o >= 1; o >>= 1) sum += __shfl_xor(sum, o);
  __shared__ float red[4], red2[4];
  int wv = tid >> 6;
  if ((tid & 63) == 0) red[wv] = sum;
  __syncthreads();
  int wb = (tid >> 7) * 2;
  float mu = (red[wb] + red[wb + 1]) * (1.f / D_);
  float dx = xv.x - mu, dy = xv.y - mu, dz = xv.z - mu, dw = xv.w - mu;
  float s2 = dx * dx + dy * dy + dz * dz + dw * dw;
#pragma unroll
  for (int o = 32; o >= 1; o >>= 1) s2 += __shfl_xor(s2, o);
  if ((tid & 63) == 0) red2[wv] = s2;
  __syncthreads();
  float var = (red2[wb] + red2[wb + 1]) * (1.f / D_);
  float rs = rsqrtf(var + EPS_);
  float4 gv = ((const float4*)g)[cg];
  float4 bv = ((const float4*)b)[cg];
  unsigned short o4[4] = { f2b(dx * rs * gv.x + bv.x), f2b(dy * rs * gv.y + bv.y),
                           f2b(dz * rs * gv.z + bv.z), f2b(dw * rs * gv.w + bv.w) };
  *(uint2*)(h + base) = *(const uint2*)o4;
}

// ================= GEMM templates =================
enum { E_QKV = 0, E_RES = 1, E_GELU = 2, E_PART = 3, E_F32 = 4 };

// stage a TRx64 bf16 tile, source-side XOR swizzle, gload_lds w16
template <int TR, int NW>
__device__ __forceinline__ void stage_tile(
    const unsigned short* __restrict__ gbase, int ldk, unsigned short* lds,
    int wave, int lane) {
#pragma unroll
  for (int q = 0; q < 4; q++) {
    int Lb = (q * NW + wave) << 10;             // wave-uniform LDS byte base
    int L = Lb + lane * 16;
    int row = L >> 7;
    int colb = (L & 127) ^ ((row & 7) << 4);    // involutive swizzle
    const unsigned short* gsrc = gbase + (size_t)row * ldk + (colb >> 1);
    __builtin_amdgcn_global_load_lds(
        (const __attribute__((address_space(1))) uint32_t*)gsrc,
        (__attribute__((address_space(3))) uint32_t*)(lds + (Lb >> 1)),
        16, 0, 0);
  }
}

// ---- 128x128 tile, 2-phase prologue-prefetch double-buffer ----
// Kext = K loop extent, ldk = row stride; split-K via blockIdx.z column offset.
template <int EPI>
__global__ __launch_bounds__(256, 2) void k_gemm128(
    const unsigned short* __restrict__ A,   // [M][ldk] bf16
    const unsigned short* __restrict__ Bt,  // [N][ldk] bf16
    const float* __restrict__ bias,
    void* __restrict__ Out,
    int Kext, int ldk, int N, int ldOut) {
  int z = blockIdx.z;
  A  += (size_t)z * Kext;                  // split-K column offset
  Bt += (size_t)z * Kext;
  int lane = threadIdx.x & 63, wave = threadIdx.x >> 6;
  int wm = wave >> 1, wn = wave & 1;
  int bx = blockIdx.x, by = blockIdx.y;

  __shared__ __align__(16) unsigned short As[2][128 * 64];
  __shared__ __align__(16) unsigned short Bs[2][128 * 64];

  const unsigned short* Ab = A + (size_t)by * 128 * ldk;
  const unsigned short* Bb = Bt + (size_t)bx * 128 * ldk;

  f32x4 acc[4][4] = {};
  int nk = Kext / 64;
  stage_tile<128, 4>(Ab, ldk, As[0], wave, lane);
  stage_tile<128, 4>(Bb, ldk, Bs[0], wave, lane);
  __syncthreads();
  for (int kt = 0; kt < nk; kt++) {
    int cur = kt & 1;
    if (kt + 1 < nk) {                     // issue next tile BEFORE compute
      stage_tile<128, 4>(Ab + (size_t)(kt + 1) * 64, ldk, As[cur ^ 1], wave, lane);
      stage_tile<128, 4>(Bb + (size_t)(kt + 1) * 64, ldk, Bs[cur ^ 1], wave, lane);
    }
    const char* Ac = (const char*)As[cur];
    const char* Bc = (const char*)Bs[cur];
#pragma unroll
    for (int kk = 0; kk < 2; kk++) {
      bf16x8 af[4], bfr[4];
#pragma unroll
      for (int mt = 0; mt < 4; mt++) {
        int row = wm * 64 + mt * 16 + (lane & 15);
        int off = ((row << 7) | (kk * 64 + ((lane >> 4) << 4))) ^ ((row & 7) << 4);
        af[mt] = *(const bf16x8*)(Ac + off);
      }
#pragma unroll
      for (int nt = 0; nt < 4; nt++) {
        int row = wn * 64 + nt * 16 + (lane & 15);
        int off = ((row << 7) | (kk * 64 + ((lane >> 4) << 4))) ^ ((row & 7) << 4);
        bfr[nt] = *(const bf16x8*)(Bc + off);
      }
#pragma unroll
      for (int mt = 0; mt < 4; mt++)
#pragma unroll
        for (int nt = 0; nt < 4; nt++)
          acc[mt][nt] = __builtin_amdgcn_mfma_f32_16x16x32_bf16(
              af[mt], bfr[nt], acc[mt][nt], 0, 0, 0);
    }
    __syncthreads();   // drains vmcnt: next tile landed while we computed
  }

  int gm = by * 128 + wm * 64;
  int gn = bx * 128 + wn * 64;
#pragma unroll
  for (int mt = 0; mt < 4; mt++) {
#pragma unroll
    for (int nt = 0; nt < 4; nt++) {
      int m0 = gm + mt * 16 + ((lane >> 4) << 2);
      int n = gn + nt * 16 + (lane & 15);
#pragma unroll
      for (int j = 0; j < 4; j++) {
        float v = acc[mt][nt][j];
        int m = m0 + j;
        if constexpr (EPI == E_QKV) {          // N=1536 -> qkv[zq][row][col]
          int zq = n >> 9, col = n & 511;
          ((unsigned short*)Out)[((size_t)zq * NROW + m) * D_ + col] = f2b(v);
        } else if constexpr (EPI == E_RES) {   // x = resid + v
          size_t idx = (size_t)m * ldOut + n;
          ((float*)Out)[idx] = bias[idx] + v;
        } else if constexpr (EPI == E_GELU) {
          size_t idx = (size_t)m * ldOut + n;
          v += bias[n];
          float u2 = 1.5957691216057308f * (v + 0.044715f * v * v * v);
          float sg = 1.f / (1.f + __expf(-u2));
          ((unsigned short*)Out)[idx] = f2b(v * sg);
        } else {                               // E_PART: parts[z][m][n]
          ((float*)Out)[(size_t)z * NROW * D_ + (size_t)m * ldOut + n] = v;
        }
      }
    }
  }
}

// ---- 256x256x64, 8 waves, single-buffer (head only) ----
__global__ __launch_bounds__(512) void k_gemm256(
    const unsigned short* __restrict__ A,
    const unsigned short* __restrict__ Bt,
    void* __restrict__ Out,
    int K, int N, int ldOut) {
  int lane = threadIdx.x & 63, wave = threadIdx.x >> 6;
  int wm = wave >> 2, wn = wave & 3;
  // supertile remap: 25 bx x 16 by groups for B-panel L2/L3 reuse (gridDim.x=125)
  int lin = blockIdx.y * 125 + blockIdx.x;
  int seg = lin / 400, rem = lin % 400;
  int bx = seg * 25 + rem % 25, by = rem / 25;

  __shared__ __align__(16) unsigned short As[256 * 64];
  __shared__ __align__(16) unsigned short Bs[256 * 64];

  const unsigned short* Ab = A + (size_t)by * 256 * K;
  const unsigned short* Bb = Bt + (size_t)bx * 256 * K;

  f32x4 acc[8][4] = {};
  int nk = K / 64;
  for (int kt = 0; kt < nk; kt++) {
    stage_tile<256, 8>(Ab + (size_t)kt * 64, K, As, wave, lane);
    stage_tile<256, 8>(Bb + (size_t)kt * 64, K, Bs, wave, lane);
    __syncthreads();
    const char* Ac = (const char*)As;
    const char* Bc = (const char*)Bs;
#pragma unroll
    for (int kk = 0; kk < 2; kk++) {
      bf16x8 af[8], bfr[4];
#pragma unroll
      for (int mt = 0; mt < 8; mt++) {
        int row = wm * 128 + mt * 16 + (lane & 15);
        int off = ((row << 7) | (kk * 64 + ((lane >> 4) << 4))) ^ ((row & 7) << 4);
        af[mt] = *(const bf16x8*)(Ac + off);
      }
#pragma unroll
      for (int nt = 0; nt < 4; nt++) {
        int row = wn * 64 + nt * 16 + (lane & 15);
        int off = ((row << 7) | (kk * 64 + ((lane >> 4) << 4))) ^ ((row & 7) << 4);
        bfr[nt] = *(const bf16x8*)(Bc + off);
      }
#pragma unroll
      for (int mt = 0; mt < 8; mt++)
#pragma unroll
        for (int nt = 0; nt < 4; nt++)
          acc[mt][nt] = __builtin_amdgcn_mfma_f32_16x16x32_bf16(
              af[mt], bfr[nt], acc[mt][nt], 0, 0, 0);
    }
    __syncthreads();
  }

  int gm = by * 256 + wm * 128;
  int gn = bx * 256 + wn * 64;
#pragma unroll
  for (int mt = 0; mt < 8; mt++) {
#pragma unroll
    for (int nt = 0; nt < 4; nt++) {
      int m0 = gm + mt * 16 + ((lane >> 4) << 2);
      int n = gn + nt * 16 + (lane & 15);
#pragma unroll
      for (int j = 0; j < 4; j++)
        ((float*)Out)[(size_t)(m0 + j) * ldOut + n] = acc[mt][nt][j];
    }
  }
}

// ---- attention phase A: G[c,h,d,k] = 0.5 * sum_rows v_d * k_k ----
__device__ __forceinline__ void unpack8f(uint4 u, float* dst) {
  dst[0] = b2f((unsigned short)(u.x & 0xffff)); dst[1] = b2f((unsigned short)(u.x >> 16));
  dst[2] = b2f((unsigned short)(u.y & 0xffff)); dst[3] = b2f((unsigned short)(u.y >> 16));
  dst[4] = b2f((unsigned short)(u.z & 0xffff)); dst[5] = b2f((unsigned short)(u.z >> 16));
  dst[6] = b2f((unsigned short)(u.w & 0xffff)); dst[7] = b2f((unsigned short)(u.w >> 16));
}

__global__ __launch_bounds__(256) void k_attnA(
    const unsigned short* __restrict__ kbuf, const unsigned short* __restrict__ vbuf,
    float* __restrict__ G) {
  int c = blockIdx.x, h = blockIdx.y;
  __shared__ __align__(16) float Ks[CROWS][HD_];
  __shared__ __align__(16) float Vs[CROWS][HD_];
  int tid = threadIdx.x;
#pragma unroll
  for (int it = 0; it < 4; it++) {
    int gi = it * 256 + tid;
    int r = gi >> 3, c8 = gi & 7;
    int bb = r & 1, tt = c * CCH + (r >> 1);
    size_t goff = ((size_t)bb * T_ + tt) * D_ + h * HD_ + c8 * 8;
    uint4 kv = *(const uint4*)(kbuf + goff);
    uint4 vv = *(const uint4*)(vbuf + goff);
    unpack8f(kv, &Ks[r][c8 * 8]);
    unpack8f(vv, &Vs[r][c8 * 8]);
  }
  __syncthreads();
  int d = tid & 63, kb = (tid >> 6) * 16;
  float acc[16] = {};
  for (int r = 0; r < CROWS; r++) {
    float vd = Vs[r][d];
#pragma unroll
    for (int j = 0; j < 16; j++) acc[j] += vd * Ks[r][kb + j];
  }
  float* Gp = G + (((size_t)c * H_ + h) * HD_ + d) * HD_ + kb;
#pragma unroll
  for (int j = 0; j < 16; j++) Gp[j] = 0.5f * acc[j];
}

// ---- attention phase B: register-resident exclusive prefix (one latency) ----
__global__ __launch_bounds__(256) void k_attnB(const float* __restrict__ G,
                                               float* __restrict__ Mem) {
  int hh = blockIdx.x >> 4, seg = blockIdx.x & 15;
  int idx = seg * 256 + threadIdx.x;
  float g[NC];
#pragma unroll
  for (int c = 0; c < NC; c++)
    g[c] = G[((size_t)c * H_ + hh) * (HD_ * HD_) + idx];
  float m = 0.f;
#pragma unroll
  for (int c = 0; c < NC; c++) {
    Mem[((size_t)c * H_ + hh) * (HD_ * HD_) + idx] = m;
    m += g[c];
  }
}

// ---- attention phase C (MFMA): Y = Q@Mem^T (hi/lo bf16) + causal(QK^T*0.5)@V ----
__global__ __launch_bounds__(256) void k_attnC(
    const unsigned short* __restrict__ qbuf, const unsigned short* __restrict__ kbuf,
    const unsigned short* __restrict__ vbuf, const float* __restrict__ Mem,
    unsigned short* __restrict__ ybuf) {
  int c = blockIdx.x, h = blockIdx.y;
  __shared__ __align__(16) unsigned short smem[32768];   // 64 KB, all XOR-swizzled
  unsigned short* Qs  = smem;            // 128x64
  unsigned short* Ksh = smem + 8192;     // 128x64
  unsigned short* Vt  = smem + 16384;    // 64x128 (V transposed)
  unsigned short* Mhi = smem + 24576;    // 64x64
  unsigned short* Mlo = smem + 28672;    // 64x64
  unsigned short* Ps  = smem;            // 128x128 overlays Qs+Ksh exactly

  int tid = threadIdx.x, lane = tid & 63, w = tid >> 6;
#pragma unroll
  for (int it = 0; it < 4; it++) {
    int gi = it * 256 + tid;
    int r = gi >> 3, g8 = gi & 7;
    int bb = r & 1, tt = c * CCH + (r >> 1);
    size_t go = ((size_t)bb * T_ + tt) * D_ + h * HD_ + g8 * 8;
    int qc = (g8 * 8) ^ ((r & 7) << 3);
    *(uint4*)(Qs + r * 64 + qc) = *(const uint4*)(qbuf + go);
    *(uint4*)(Ksh + r * 64 + qc) = *(const uint4*)(kbuf + go);
    uint4 vv = *(const uint4*)(vbuf + go);
    const unsigned short* vp = (const unsigned short*)&vv;
#pragma unroll
    for (int j = 0; j < 8; j++) {
      int d = g8 * 8 + j;
      int t = (d & 7) ^ (d >> 3);
      Vt[d * 128 + (r ^ (t << 3))] = vp[j];
    }
  }
  {
    const float* Mp = Mem + (((size_t)c * H_ + h) << 12);
#pragma unroll
    for (int it = 0; it < 16; it++) {
      int i = it * 256 + tid;
      int d = i >> 6, k = i & 63;
      float m = Mp[i];
      unsigned short hi = f2b(m);
      float lo = m - b2f(hi);
      int col = k ^ ((d & 7) << 3);
      Mhi[d * 64 + col] = hi;
      Mlo[d * 64 + col] = f2b(lo);
    }
  }
  __syncthreads();

  int row0 = w * 32;
  f32x4 sacc[2][8] = {};
  f32x4 yacc[2][4] = {};
#pragma unroll
  for (int kk = 0; kk < 2; kk++) {
    bf16x8 aq[2];
#pragma unroll
    for (int mt = 0; mt < 2; mt++) {
      int row = row0 + mt * 16 + (lane & 15);
      aq[mt] = *(const bf16x8*)(Qs + row * 64 +
                ((kk * 32 + ((lane >> 4) << 3)) ^ ((row & 7) << 3)));
    }
#pragma unroll
    for (int nt = 0; nt < 8; nt++) {
      int row = nt * 16 + (lane & 15);
      bf16x8 bk = *(const bf16x8*)(Ksh + row * 64 +
                ((kk * 32 + ((lane >> 4) << 3)) ^ ((row & 7) << 3)));
#pragma unroll
      for (int mt = 0; mt < 2; mt++)
        sacc[mt][nt] = __builtin_amdgcn_mfma_f32_16x16x32_bf16(aq[mt], bk,
                                                               sacc[mt][nt], 0, 0, 0);
    }
#pragma unroll
    for (int nt = 0; nt < 4; nt++) {
      int row = nt * 16 + (lane & 15);
      int off = row * 64 + ((kk * 32 + ((lane >> 4) << 3)) ^ ((row & 7) << 3));
      bf16x8 bh = *(const bf16x8*)(Mhi + off);
      bf16x8 bl = *(const bf16x8*)(Mlo + off);
#pragma unroll
      for (int mt = 0; mt < 2; mt++) {
        yacc[mt][nt] = __builtin_amdgcn_mfma_f32_16x16x32_bf16(aq[mt], bh,
                                                               yacc[mt][nt], 0, 0, 0);
        yacc[mt][nt] = __builtin_amdgcn_mfma_f32_16x16x32_bf16(aq[mt], bl,
                                                               yacc[mt][nt], 0, 0, 0);
      }
    }
  }
  __syncthreads();

#pragma unroll
  for (int mt = 0; mt < 2; mt++)
#pragma unroll
    for (int nt = 0; nt < 8; nt++)
#pragma unroll
      for (int j = 0; j < 4; j++) {
        int qr = row0 + mt * 16 + ((lane >> 4) << 2) + j;
        int ks = nt * 16 + (lane & 15);
        float v = ((ks >> 1) <= (qr >> 1)) ? sacc[mt][nt][j] * 0.5f : 0.f;
        Ps[qr * 128 + (ks ^ ((qr & 7) << 3))] = f2b(v);
      }
  __syncthreads();

  for (int kb = 0; kb <= w; kb++) {
    bf16x8 ap[2];
#pragma unroll
    for (int mt = 0; mt < 2; mt++) {
      int row = row0 + mt * 16 + (lane & 15);
      ap[mt] = *(const bf16x8*)(Ps + row * 128 +
                ((kb * 32 + ((lane >> 4) << 3)) ^ ((row & 7) << 3)));
    }
#pragma unroll
    for (int nt = 0; nt < 4; nt++) {
      int d = nt * 16 + (lane & 15);
      int t = (d & 7) ^ (d >> 3);
      int gb = (kb * 32 + ((lane >> 4) << 3)) ^ (t << 3);
      bf16x8 bv = *(const bf16x8*)(Vt + d * 128 + gb);
#pragma unroll
      for (int mt = 0; mt < 2; mt++)
        yacc[mt][nt] = __builtin_amdgcn_mfma_f32_16x16x32_bf16(ap[mt], bv,
                                                               yacc[mt][nt], 0, 0, 0);
    }
  }

#pragma unroll
  for (int mt = 0; mt < 2; mt++)
#pragma unroll
    for (int nt = 0; nt < 4; nt++)
#pragma unroll
      for (int j = 0; j < 4; j++) {
        int qr = row0 + mt * 16 + ((lane >> 4) << 2) + j;
        int d = nt * 16 + (lane & 15);
        int bb = qr & 1, tl = qr >> 1;
        ybuf[((size_t)bb * T_ + c * CCH + tl) * D_ + h * HD_ + d] =
            f2b(yacc[mt][nt][j]);
      }
}

extern "C" void kernel_launch(void* const* d_in, const int* in_sizes, int n_in,
                              void* d_out, int out_size, void* d_ws, size_t ws_size,
                              hipStream_t stream) {
  (void)in_sizes; (void)n_in; (void)out_size; (void)ws_size;
  const float* emb  = (const float*)d_in[0];
  const float* pos  = (const float*)d_in[1];
  const float* ln1g = (const float*)d_in[2];
  const float* ln1b = (const float*)d_in[3];
  const float* Wq   = (const float*)d_in[4];
  const float* Wk   = (const float*)d_in[5];
  const float* Wv   = (const float*)d_in[6];
  const float* Wo   = (const float*)d_in[7];
  const float* ln2g = (const float*)d_in[8];
  const float* ln2b = (const float*)d_in[9];
  const float* W1   = (const float*)d_in[10];
  const float* b1   = (const float*)d_in[11];
  const float* W2   = (const float*)d_in[12];
  const float* b2   = (const float*)d_in[13];
  const float* lnfg = (const float*)d_in[14];
  const float* lnfb = (const float*)d_in[15];
  const int*   ids  = (const int*)d_in[16];

  char* w = (char*)d_ws;
  size_t off = 0;
  auto alloc = [&](size_t bytes) -> void* {
    void* p = w + off; off += (bytes + 255) & ~(size_t)255; return p;
  };
  const size_t DD = (size_t)D_ * D_;
  unsigned short* WqkvT = (unsigned short*)alloc(12ull * DD * 2);
  unsigned short* WoT   = (unsigned short*)alloc(4ull * DD * 2);
  unsigned short* W1T   = (unsigned short*)alloc((size_t)L_ * NL_ * HID_ * D_ * 2);
  unsigned short* W2cat = (unsigned short*)alloc((size_t)L_ * D_ * NL_ * HID_ * 2);
  unsigned short* embB  = (unsigned short*)alloc((size_t)V_ * D_ * 2);
  float* bsum           = (float*)alloc((size_t)L_ * D_ * 4);
  float* x              = (float*)alloc((size_t)NROW * D_ * 4);
  unsigned short* h     = (unsigned short*)alloc((size_t)NROW * D_ * 2);
  // qkv+ybuf+G+Mem = 24 MB contiguous; dead during CMS -> split-K partials overlay
  unsigned short* qkv   = (unsigned short*)alloc(3ull * NROW * D_ * 2);   // 12 MB
  unsigned short* ybuf  = (unsigned short*)alloc((size_t)NROW * D_ * 2);  //  4 MB
  float* G              = (float*)alloc((size_t)NC * H_ * HD_ * HD_ * 4); //  4 MB
  float* Mem            = (float*)alloc((size_t)NC * H_ * HD_ * HD_ * 4); //  4 MB
  float* parts          = (float*)qkv;
  unsigned short* hmid  = (unsigned short*)alloc((size_t)NROW * NL_ * HID_ * 2);

  dim3 blk(256);
  k_prep<<<dim3(46728), blk, 0, stream>>>(emb, pos, ids, Wq, Wk, Wv, Wo, W1, W2, b2,
                                          ln1g, ln1b,
                                          WqkvT, WoT, W1T, W2cat, embB, bsum, x, h);

  unsigned short* qb = qkv;
  unsigned short* kb = qkv + (size_t)NROW * D_;
  unsigned short* vb = qkv + 2ull * NROW * D_;

  for (int l = 0; l < L_; l++) {
    // h holds LN1(x) (from prep for l=0, from k_cmsred_ln otherwise)
    k_gemm128<E_QKV><<<dim3(12, 32), blk, 0, stream>>>(
        h, WqkvT + (size_t)l * 3 * DD, bsum, qkv, D_, D_, 3 * D_, D_);
    k_attnA<<<dim3(NC, H_), blk, 0, stream>>>(kb, vb, G);
    k_attnB<<<dim3(H_ * 16), blk, 0, stream>>>(G, Mem);
    k_attnC<<<dim3(NC, H_), blk, 0, stream>>>(qb, kb, vb, Mem, ybuf);
    k_gemm128<E_RES><<<dim3(4, 32), blk, 0, stream>>>(
        ybuf, WoT + (size_t)l * DD, x, x, D_, D_, D_, D_);
    k_ln<<<dim3(NROW), dim3(128), 0, stream>>>(x, ln2g + l * D_, ln2b + l * D_, h);
    k_gemm128<E_GELU><<<dim3(48, 32), blk, 0, stream>>>(
        h, W1T + (size_t)l * NL_ * HID_ * D_, b1 + (size_t)l * NL_ * HID_, hmid,
        D_, D_, NL_ * HID_, NL_ * HID_);
    k_gemm128<E_PART><<<dim3(4, 32, 3), blk, 0, stream>>>(
        hmid, W2cat + (size_t)l * D_ * NL_ * HID_, bsum, parts,
        2048, NL_ * HID_, D_, D_);
    const float* gn = (l < 3) ? (ln1g + (l + 1) * D_) : lnfg;
    const float* bn = (l < 3) ? (ln1b + (l + 1) * D_) : lnfb;
    k_cmsred_ln<<<dim3(NROW / 2), blk, 0, stream>>>(x, parts, bsum + l * D_, gn, bn, h);
  }
  k_gemm256<<<dim3(125, 16), dim3(512), 0, stream>>>(h, embB, d_out, D_, V_, V_);
}